// Round 5
// baseline (221.544 us; speedup 1.0000x reference)
//
#include <hip/hip_runtime.h>

#define N_NODES 50000
#define NCH 256          // edge chunks (blocks in count/scatter)
#define NBKT 256         // bucket slots (dst>>8; 196 live for N=50000)

typedef short bf16x8 __attribute__((ext_vector_type(8)));
typedef float f32x4 __attribute__((ext_vector_type(4)));

__device__ inline unsigned short f2bf(float f) {
    union { float f; unsigned u; } v; v.f = f;
    unsigned u = v.u;
    unsigned lsb = (u >> 16) & 1u;
    u += 0x7fffu + lsb;  // round-to-nearest-even
    return (unsigned short)(u >> 16);
}

__device__ inline float bf2f(unsigned short h) {
    union { unsigned u; float f; } v; v.u = ((unsigned)h) << 16;
    return v.f;
}

// ============ prep: bucket histogram (blocks < NCH) + W split (blocks >= NCH) ============
__global__ __launch_bounds__(256) void prep(const int* __restrict__ dst,
                                            int* __restrict__ cnt, int E, int epc,
                                            const float* __restrict__ W1,
                                            const float* __restrict__ W2,
                                            unsigned short* __restrict__ B1h,
                                            unsigned short* __restrict__ B1l,
                                            unsigned short* __restrict__ B2h,
                                            unsigned short* __restrict__ B2l) {
    const int c = blockIdx.x;
    if (c < NCH) {
        __shared__ int h[NBKT];
        h[threadIdx.x] = 0;
        __syncthreads();
        const int e0 = c * epc;
        const int e1 = min(E, e0 + epc);
        for (int e = e0 + threadIdx.x; e < e1; e += 256)
            atomicAdd(&h[dst[e] >> 8], 1);
        __syncthreads();
        cnt[c * NBKT + threadIdx.x] = h[threadIdx.x];
        return;
    }
    // W split into MFMA fragment order
    int i = (c - NCH) * 256 + threadIdx.x;
    const float* W;
    unsigned short *Th, *Tl;
    int K, logM, idx;
    if (i < 32768) { W = W1; Th = B1h; Tl = B1l; K = 256; logM = 7; idx = i; }
    else if (i < 32768 + 8192) { W = W2; Th = B2h; Tl = B2l; K = 128; logM = 6; idx = i - 32768; }
    else return;
    const int M = 1 << logM;
    const int KS = K / 32;
    int k = idx >> logM;
    int n = idx & (M - 1);
    float v = W[idx];
    unsigned short h = f2bf(v);
    unsigned short l = f2bf(v - bf2f(h));
    int g = n >> 4, n16 = n & 15, ks = k >> 5, quad = (k >> 3) & 3, j = k & 7;
    size_t o = ((size_t)((g * KS + ks) * 64 + quad * 16 + n16)) * 8 + j;
    Th[o] = h;
    Tl[o] = l;
}

// S1: per-bucket exclusive scan over chunks; off[c][b], total[b]
__global__ __launch_bounds__(256) void bkt_scan_chunks(const int* __restrict__ cnt,
                                                       int* __restrict__ off,
                                                       int* __restrict__ total) {
    __shared__ int sh[256];
    const int b = blockIdx.x;
    const int t = threadIdx.x;
    int v = cnt[t * NBKT + b];
    sh[t] = v;
    __syncthreads();
    for (int o = 1; o < 256; o <<= 1) {
        int u = (t >= o) ? sh[t - o] : 0;
        __syncthreads();
        sh[t] += u;
        __syncthreads();
    }
    off[t * NBKT + b] = sh[t] - v;
    if (t == 255) total[b] = sh[255];
}

// B2: scatter packed (src<<8 | dst&255) into bucket-sorted order; LDS cursors.
__global__ __launch_bounds__(256) void bkt_scatter(const int* __restrict__ src,
                                                   const int* __restrict__ dst,
                                                   const int* __restrict__ off,
                                                   const int* __restrict__ total,
                                                   unsigned* __restrict__ pairs,
                                                   int E, int epc) {
    __shared__ int sh[256];
    __shared__ int cur[NBKT];
    const int c = blockIdx.x;
    const int t = threadIdx.x;
    int v = total[t];
    sh[t] = v;
    __syncthreads();
    for (int o = 1; o < 256; o <<= 1) {
        int u = (t >= o) ? sh[t - o] : 0;
        __syncthreads();
        sh[t] += u;
        __syncthreads();
    }
    cur[t] = (sh[t] - v) + off[c * NBKT + t];   // bbase[t] + off[c][t]
    __syncthreads();
    const int e0 = c * epc;
    const int e1 = min(E, e0 + epc);
    for (int e = e0 + t; e < e1; e += 256) {
        int s = src[e];
        int d = dst[e];
        int pos = atomicAdd(&cur[d >> 8], 1);
        pairs[pos] = ((unsigned)s << 8) | (unsigned)(d & 255);
    }
}

// B3: per-bucket local CSR: rowptr, dinv, csr_src (dense regional writes).
__global__ __launch_bounds__(256) void bkt_csr(const unsigned* __restrict__ pairs,
                                               const int* __restrict__ total,
                                               int* __restrict__ rowptr,
                                               int* __restrict__ csr_src,
                                               float* __restrict__ dinv, int N) {
    __shared__ int lh[256];
    __shared__ int sc[256];
    __shared__ int lcur[256];
    const int b = blockIdx.x;
    const int t = threadIdx.x;

    sc[t] = total[t];
    __syncthreads();
    for (int o = 1; o < 256; o <<= 1) {
        int u = (t >= o) ? sc[t - o] : 0;
        __syncthreads();
        sc[t] += u;
        __syncthreads();
    }
    const int eend = sc[b];
    const int ebase = eend - total[b];
    const int node0 = b << 8;

    lh[t] = 0;
    __syncthreads();
    for (int e = ebase + t; e < eend; e += 256)
        atomicAdd(&lh[pairs[e] & 255u], 1);
    __syncthreads();
    int v = lh[t];
    sc[t] = v;
    __syncthreads();
    for (int o = 1; o < 256; o <<= 1) {
        int u = (t >= o) ? sc[t - o] : 0;
        __syncthreads();
        sc[t] += u;
        __syncthreads();
    }
    const int excl = sc[t] - v;
    lcur[t] = ebase + excl;
    const int node = node0 + t;
    if (node <= N) {
        rowptr[node] = ebase + excl;            // node==N: rowptr[N]=E
        if (node < N) dinv[node] = rsqrtf((float)(v + 1));  // +1 self-loop
    }
    __syncthreads();
    for (int e = ebase + t; e < eend; e += 256) {
        unsigned p = pairs[e];
        int pos = atomicAdd(&lcur[p & 255u], 1);
        csr_src[pos] = (int)(p >> 8);
    }
}

// ============ MFMA GEMM (layer1): fp32 A -> 3-term split, 32x32/wave,
//              rolling B, dbuf LDS; writes hn1b in 4-PLANE layout:
//              plane q = channels [32q,32q+32), Cb[q*(N*32) + row*32 + (ch&31)] ============
template <int K, int M>
__global__ __launch_bounds__(M * 4) void gemm_mfma_v4(const float* __restrict__ A,
                                                      const unsigned short* __restrict__ Bfh,
                                                      const unsigned short* __restrict__ Bfl,
                                                      const float* __restrict__ dinv,
                                                      unsigned short* __restrict__ Cb, int N) {
    const int KS = K / 32;
    const int THREADS = M * 4;
    const int CPT = 512 / THREADS;
    const int PL = 64 * 40;
    const int CPAIRS = M / 32;

    __shared__ __align__(16) unsigned short Ah[2 * PL];
    __shared__ __align__(16) unsigned short Al[2 * PL];

    const int tid = threadIdx.x;
    const int wave = tid >> 6;
    const int lane = tid & 63;
    const int n16 = lane & 15;
    const int quad = lane >> 4;
    const int cpair = wave & (CPAIRS - 1);
    const int rpair = wave / CPAIRS;
    const int row0 = blockIdx.x * 64;

    bf16x8 bh[2][2], bl[2][2];
    auto loadB = [&](int ks, int par) {
#pragma unroll
        for (int ct = 0; ct < 2; ct++) {
            const int g = cpair * 2 + ct;
            const size_t o = ((size_t)(g * KS + ks) * 64 + lane) * 8;
            bh[par][ct] = *(const bf16x8*)(Bfh + o);
            bl[par][ct] = *(const bf16x8*)(Bfl + o);
        }
    };
    loadB(0, 0);

    int srow[CPT], sc4[CPT];
    const float* aptr[CPT];
#pragma unroll
    for (int p = 0; p < CPT; p++) {
        int q = p * THREADS + tid;
        srow[p] = q >> 3;
        sc4[p] = q & 7;
        int grow = row0 + srow[p];
        if (grow >= N) grow = N - 1;
        aptr[p] = A + (size_t)grow * K + sc4[p] * 4;
    }

    float4 pre[CPT];
#pragma unroll
    for (int p = 0; p < CPT; p++) pre[p] = *(const float4*)(aptr[p]);

#pragma unroll
    for (int p = 0; p < CPT; p++) {
        ushort4 h4, l4;
        unsigned short* hp = (unsigned short*)&h4;
        unsigned short* lp = (unsigned short*)&l4;
        float av[4] = {pre[p].x, pre[p].y, pre[p].z, pre[p].w};
#pragma unroll
        for (int j = 0; j < 4; j++) {
            unsigned short h = f2bf(av[j]);
            hp[j] = h;
            lp[j] = f2bf(av[j] - bf2f(h));
        }
        *(ushort4*)(Ah + srow[p] * 40 + sc4[p] * 4) = h4;
        *(ushort4*)(Al + srow[p] * 40 + sc4[p] * 4) = l4;
    }
    if (KS > 1) {
#pragma unroll
        for (int p = 0; p < CPT; p++) pre[p] = *(const float4*)(aptr[p] + 32);
    }
    __syncthreads();

    f32x4 acc[2][2] = {};

#pragma unroll
    for (int ks = 0; ks < KS; ks++) {
        const int cur = ks & 1;
        if (ks + 1 < KS) loadB(ks + 1, cur ^ 1);
#pragma unroll
        for (int rt = 0; rt < 2; rt++) {
            const int ro = cur * PL + (rpair * 32 + rt * 16 + n16) * 40 + quad * 8;
            bf16x8 ah = *(const bf16x8*)(Ah + ro);
            bf16x8 al = *(const bf16x8*)(Al + ro);
#pragma unroll
            for (int ct = 0; ct < 2; ct++) {
                acc[rt][ct] = __builtin_amdgcn_mfma_f32_16x16x32_bf16(ah, bh[cur][ct], acc[rt][ct], 0, 0, 0);
                acc[rt][ct] = __builtin_amdgcn_mfma_f32_16x16x32_bf16(ah, bl[cur][ct], acc[rt][ct], 0, 0, 0);
                acc[rt][ct] = __builtin_amdgcn_mfma_f32_16x16x32_bf16(al, bh[cur][ct], acc[rt][ct], 0, 0, 0);
            }
        }
        if (ks + 1 < KS) {
            const int nxt = (cur ^ 1) * PL;
#pragma unroll
            for (int p = 0; p < CPT; p++) {
                ushort4 h4, l4;
                unsigned short* hp = (unsigned short*)&h4;
                unsigned short* lp = (unsigned short*)&l4;
                float av[4] = {pre[p].x, pre[p].y, pre[p].z, pre[p].w};
#pragma unroll
                for (int j = 0; j < 4; j++) {
                    unsigned short h = f2bf(av[j]);
                    hp[j] = h;
                    lp[j] = f2bf(av[j] - bf2f(h));
                }
                *(ushort4*)(Ah + nxt + srow[p] * 40 + sc4[p] * 4) = h4;
                *(ushort4*)(Al + nxt + srow[p] * 40 + sc4[p] * 4) = l4;
            }
            if (ks + 2 < KS) {
#pragma unroll
                for (int p = 0; p < CPT; p++)
                    pre[p] = *(const float4*)(aptr[p] + (ks + 2) * 32);
            }
        }
        __syncthreads();
    }

#pragma unroll
    for (int rt = 0; rt < 2; rt++) {
#pragma unroll
        for (int ct = 0; ct < 2; ct++) {
            const int col = cpair * 32 + ct * 16 + n16;
            const int rbase = row0 + rpair * 32 + rt * 16 + quad * 4;
#pragma unroll
            for (int r = 0; r < 4; r++) {
                int orow = rbase + r;
                if (orow < N) {
                    unsigned short ob = f2bf(dinv[orow] * acc[rt][ct][r]);
                    // planar: plane = col>>5 (32-ch planes)
                    Cb[(size_t)(col >> 5) * ((size_t)N_NODES * 32) +
                       (size_t)orow * 32 + (col & 31)] = ob;
                }
            }
        }
    }
}

// ============ FUSED: gather1(+ReLU+bias) -> LDS A-tile -> GEMM layer2 ============
// 512 threads. Gather runs FOUR plane passes (32 ch each): per-pass random working
// set = 3.2 MB < 4 MiB per-XCD L2 -> re-reads are L2 hits (latency ~200 vs ~900 cyc).
// Thread layout per pass: (row r 0..63, edge-half h 0..1, 8-ch slice j4 0..3); the
// two halves combine through an LDS partial (also halves the dependent chain).
// After the final barrier, waves 0-3 run the resident-A GEMM; waves 4-7 exit.
template <int K, int M>   // K=128 (h1 cols), M=64 (out cols)
__global__ __launch_bounds__(512) void gather_gemm2(const unsigned short* __restrict__ hnb,
                                                    const int* __restrict__ rowptr,
                                                    const int* __restrict__ csr_src,
                                                    const float* __restrict__ dinv,
                                                    const float* __restrict__ bias,
                                                    const unsigned short* __restrict__ Bfh,
                                                    const unsigned short* __restrict__ Bfl,
                                                    unsigned short* __restrict__ Cb, int N) {
    const int KS = K / 32;          // 4 (= #planes of hn1b)
    const int CPAIRS = M / 32;      // 2
    const int PLP = 64 * 40;        // LDS panel elems (64 rows x 32 cols, stride 40)
    const size_t PLANE1 = (size_t)N_NODES * 32;   // hn1b plane stride (elems)
    const size_t PLANE2 = (size_t)N_NODES * 32;   // hn2b plane stride (elems)

    __shared__ __align__(16) unsigned short Ah[KS * PLP];   // 20 KB
    __shared__ float Psum[64 * 4 * 8];                      // 8 KB (h=1 partials)

    const int tid = threadIdx.x;
    const int wave = tid >> 6;
    const int lane = tid & 63;
    const int n16 = lane & 15;
    const int quad = lane >> 4;
    const int cpair = wave & (CPAIRS - 1);   // waves 0-3 only
    const int rpair = wave / CPAIRS;
    const int row0 = blockIdx.x * 64;

    bf16x8 bh[2][2], bl[2][2];
    auto loadB = [&](int ks, int par) {
#pragma unroll
        for (int ct = 0; ct < 2; ct++) {
            const int g = cpair * 2 + ct;
            const size_t o = ((size_t)(g * KS + ks) * 64 + lane) * 8;
            bh[par][ct] = *(const bf16x8*)(Bfh + o);
            bl[par][ct] = *(const bf16x8*)(Bfl + o);
        }
    };
    if (wave < 4) loadB(0, 0);   // in flight during the gather phase

    // ---- phase 1: 4 plane passes with edge-half split ----
    {
        const int j4 = tid & 3;          // 8-ch slice within 32-ch plane
        const int h  = (tid >> 2) & 1;   // edge-half
        const int r  = tid >> 3;         // node-local row, [0,64)
        const int g  = row0 + r;
        float* ps = Psum + (r * 4 + j4) * 8;
        int e0 = 0, emid = 0, eend = 0;
        float dv = 0.0f;
        if (g < N) {
            e0 = rowptr[g];
            eend = rowptr[g + 1];
            emid = e0 + ((eend - e0) >> 1);
            dv = dinv[g];
        }
        for (int p = 0; p < KS; p++) {
            float acc[8] = {0.f, 0.f, 0.f, 0.f, 0.f, 0.f, 0.f, 0.f};
            if (g < N) {
                const unsigned short* plane = hnb + (size_t)p * PLANE1 + j4 * 8;
                int e, ee;
                if (h == 0) {
                    // self-loop + first half
                    bf16x8 v = *(const bf16x8*)(plane + (size_t)g * 32);
#pragma unroll
                    for (int i = 0; i < 8; i++) acc[i] = bf2f((unsigned short)v[i]);
                    e = e0; ee = emid;
                } else {
                    e = emid; ee = eend;
                }
                for (; e + 3 < ee; e += 4) {
                    int s0 = csr_src[e];
                    int s1 = csr_src[e + 1];
                    int s2 = csr_src[e + 2];
                    int s3 = csr_src[e + 3];
                    bf16x8 v0 = *(const bf16x8*)(plane + (size_t)s0 * 32);
                    bf16x8 v1 = *(const bf16x8*)(plane + (size_t)s1 * 32);
                    bf16x8 v2 = *(const bf16x8*)(plane + (size_t)s2 * 32);
                    bf16x8 v3 = *(const bf16x8*)(plane + (size_t)s3 * 32);
#pragma unroll
                    for (int i = 0; i < 8; i++) {
                        acc[i] += (bf2f((unsigned short)v0[i]) + bf2f((unsigned short)v1[i])) +
                                  (bf2f((unsigned short)v2[i]) + bf2f((unsigned short)v3[i]));
                    }
                }
                for (; e < ee; e++) {
                    int s0 = csr_src[e];
                    bf16x8 v0 = *(const bf16x8*)(plane + (size_t)s0 * 32);
#pragma unroll
                    for (int i = 0; i < 8; i++) acc[i] += bf2f((unsigned short)v0[i]);
                }
            }
            if (h == 1) {
#pragma unroll
                for (int i = 0; i < 8; i++) ps[i] = acc[i];
            }
            __syncthreads();
            if (h == 0) {
                unsigned short* ldst = Ah + p * PLP + r * 40 + j4 * 8;
                bf16x8 rr;
                if (g < N) {
#pragma unroll
                    for (int i = 0; i < 8; i++) {
                        float t = dv * (acc[i] + ps[i]) + bias[p * 32 + j4 * 8 + i];
                        rr[i] = (short)f2bf(fmaxf(t, 0.0f));  // ReLU
                    }
                } else {
                    rr = bf16x8{};
                }
                *(bf16x8*)ldst = rr;
            }
            __syncthreads();
        }
    }
    if (wave >= 4) return;   // gather-only waves done; no further barriers below

    // ---- phase 2: GEMM over resident A-tile (waves 0-3) ----
    f32x4 acc[2][2] = {};
#pragma unroll
    for (int ks = 0; ks < KS; ks++) {
        const int cur = ks & 1;
        if (ks + 1 < KS) loadB(ks + 1, cur ^ 1);
#pragma unroll
        for (int rt = 0; rt < 2; rt++) {
            const int ro = ks * PLP + (rpair * 32 + rt * 16 + n16) * 40 + quad * 8;
            bf16x8 ah = *(const bf16x8*)(Ah + ro);
#pragma unroll
            for (int ct = 0; ct < 2; ct++) {
                acc[rt][ct] = __builtin_amdgcn_mfma_f32_16x16x32_bf16(ah, bh[cur][ct], acc[rt][ct], 0, 0, 0);
                acc[rt][ct] = __builtin_amdgcn_mfma_f32_16x16x32_bf16(ah, bl[cur][ct], acc[rt][ct], 0, 0, 0);
            }
        }
    }

#pragma unroll
    for (int rt = 0; rt < 2; rt++) {
#pragma unroll
        for (int ct = 0; ct < 2; ct++) {
            const int col = cpair * 32 + ct * 16 + n16;
            const int rbase = row0 + rpair * 32 + rt * 16 + quad * 4;
#pragma unroll
            for (int r = 0; r < 4; r++) {
                int orow = rbase + r;
                if (orow < N) {
                    unsigned short ob = f2bf(dinv[orow] * acc[rt][ct][r]);
                    // hn2b planar: 2 planes of 32 ch
                    Cb[(size_t)(col >> 5) * PLANE2 + (size_t)orow * 32 + (col & 31)] = ob;
                }
            }
        }
    }
}

// ============ gather-aggregate (planar bf16 in) -> fp32 out (no ReLU) ============
// hnb is PLANAR: M/32 planes of [N][32]. Two passes, 3.2 MB working set each.
template <int M>
__global__ __launch_bounds__(256) void gather_to_f32(const unsigned short* __restrict__ hnb,
                                                     const int* __restrict__ rowptr,
                                                     const int* __restrict__ csr_src,
                                                     const float* __restrict__ dinv,
                                                     const float* __restrict__ bias,
                                                     float* __restrict__ outp, int n) {
    const int NP = M / 32;           // planes (2 for M=64)
    const int MQ = 4;                // 8-ch slices per plane
    const int GPB = 256 / MQ;        // 64 nodes/block
    const size_t PLANE = (size_t)N_NODES * 32;
    int g = blockIdx.x * GPB + threadIdx.x / MQ;
    int j = threadIdx.x % MQ;
    if (g >= n) return;

    const int e0 = rowptr[g];
    const int eend = rowptr[g + 1];
    const float s = dinv[g];

    for (int p = 0; p < NP; p++) {
        const unsigned short* plane = hnb + (size_t)p * PLANE + j * 8;
        float acc[8];
        {
            bf16x8 v = *(const bf16x8*)(plane + (size_t)g * 32);  // self-loop
#pragma unroll
            for (int i = 0; i < 8; i++) acc[i] = bf2f((unsigned short)v[i]);
        }
        int e = e0;
        for (; e + 3 < eend; e += 4) {
            int s0 = csr_src[e];
            int s1 = csr_src[e + 1];
            int s2 = csr_src[e + 2];
            int s3 = csr_src[e + 3];
            bf16x8 v0 = *(const bf16x8*)(plane + (size_t)s0 * 32);
            bf16x8 v1 = *(const bf16x8*)(plane + (size_t)s1 * 32);
            bf16x8 v2 = *(const bf16x8*)(plane + (size_t)s2 * 32);
            bf16x8 v3 = *(const bf16x8*)(plane + (size_t)s3 * 32);
#pragma unroll
            for (int i = 0; i < 8; i++) {
                acc[i] += (bf2f((unsigned short)v0[i]) + bf2f((unsigned short)v1[i])) +
                          (bf2f((unsigned short)v2[i]) + bf2f((unsigned short)v3[i]));
            }
        }
        for (; e < eend; e++) {
            int s0 = csr_src[e];
            bf16x8 v0 = *(const bf16x8*)(plane + (size_t)s0 * 32);
#pragma unroll
            for (int i = 0; i < 8; i++) acc[i] += bf2f((unsigned short)v0[i]);
        }

        float r[8];
#pragma unroll
        for (int i = 0; i < 8; i++) r[i] = s * acc[i] + bias[p * 32 + j * 8 + i];
        float* op = outp + (size_t)g * M + p * 32 + j * 8;
        *(float4*)(op) = make_float4(r[0], r[1], r[2], r[3]);
        *(float4*)(op + 4) = make_float4(r[4], r[5], r[6], r[7]);
    }
}

extern "C" void kernel_launch(void* const* d_in, const int* in_sizes, int n_in,
                              void* d_out, int out_size, void* d_ws, size_t ws_size,
                              hipStream_t stream) {
    const float* x  = (const float*)d_in[0];
    const int*   ei = (const int*)d_in[1];
    const float* W1 = (const float*)d_in[2];
    const float* b1 = (const float*)d_in[3];
    const float* W2 = (const float*)d_in[4];
    const float* b2 = (const float*)d_in[5];

    const int N = N_NODES;
    const int E = in_sizes[1] / 2;
    const int* src = ei;
    const int* dst = ei + E;

    char* ws = (char*)d_ws;
    size_t off = 0;
    auto carve = [&](size_t bytes) {
        char* p = ws + off;
        off += (bytes + 255) & ~(size_t)255;
        return p;
    };
    int*      cnt     = (int*)     carve((size_t)NCH * NBKT * 4);
    int*      offm    = (int*)     carve((size_t)NCH * NBKT * 4);
    int*      total   = (int*)     carve((size_t)NBKT * 4);
    unsigned* pairs   = (unsigned*)carve((size_t)E * 4);
    int*      rowptr  = (int*)     carve((size_t)(N + 1) * 4);
    int*      csr_src = (int*)     carve((size_t)E * 4);
    float*    dinv    = (float*)   carve((size_t)N * 4);
    unsigned short* W1th = (unsigned short*)carve((size_t)256 * 128 * 2);
    unsigned short* W1tl = (unsigned short*)carve((size_t)256 * 128 * 2);
    unsigned short* W2th = (unsigned short*)carve((size_t)128 * 64 * 2);
    unsigned short* W2tl = (unsigned short*)carve((size_t)128 * 64 * 2);
    unsigned short* hn1b = (unsigned short*)carve((size_t)N * 128 * 2);  // bf16, PLANAR 4x[N][32]
    unsigned short* hn2b = (unsigned short*)carve((size_t)N * 64 * 2);   // bf16, PLANAR 2x[N][32]

    const int epc = (E + NCH - 1) / NCH;
    const int nbk = (N + 255) >> 8;  // 196 live buckets
    const int GB = (N + 63) / 64;    // 782 row-tiles

    // ---- CSR build + weight split ----
    prep<<<NCH + 160, 256, 0, stream>>>(dst, cnt, E, epc, W1, W2, W1th, W1tl, W2th, W2tl);
    bkt_scan_chunks<<<NBKT, 256, 0, stream>>>(cnt, offm, total);
    bkt_scatter<<<NCH, 256, 0, stream>>>(src, dst, offm, total, pairs, E, epc);
    bkt_csr<<<nbk, 256, 0, stream>>>(pairs, total, rowptr, csr_src, dinv, N);

    // ---- layer 1 transform (planar out) ----
    gemm_mfma_v4<256, 128><<<GB, 512, 0, stream>>>(x, W1th, W1tl, dinv, hn1b, N);

    // ---- layer 1 aggregate (+ReLU) fused with layer 2 transform (4 plane passes) ----
    gather_gemm2<128, 64><<<GB, 512, 0, stream>>>(hn1b, rowptr, csr_src, dinv, b1,
                                                  W2th, W2tl, hn2b, N);

    // ---- layer 2 aggregate -> fp32 out (2 plane passes) ----
    gather_to_f32<64><<<GB, 256, 0, stream>>>(hn2b, rowptr, csr_src, dinv, b2,
                                              (float*)d_out, N);
}

// Round 6
// 208.185 us; speedup vs baseline: 1.0642x; 1.0642x over previous
//
#include <hip/hip_runtime.h>

#define N_NODES 50000
#define NCH 256          // edge chunks (blocks in count/scatter)
#define NBKT 256         // bucket slots (dst>>8; 196 live for N=50000)

typedef short bf16x8 __attribute__((ext_vector_type(8)));
typedef float f32x4 __attribute__((ext_vector_type(4)));

__device__ inline unsigned short f2bf(float f) {
    union { float f; unsigned u; } v; v.f = f;
    unsigned u = v.u;
    unsigned lsb = (u >> 16) & 1u;
    u += 0x7fffu + lsb;  // round-to-nearest-even
    return (unsigned short)(u >> 16);
}

__device__ inline float bf2f(unsigned short h) {
    union { unsigned u; float f; } v; v.u = ((unsigned)h) << 16;
    return v.f;
}

// ============ prep: bucket histogram (blocks < NCH) + W split (blocks >= NCH) ============
__global__ __launch_bounds__(256) void prep(const int* __restrict__ dst,
                                            int* __restrict__ cnt, int E, int epc,
                                            const float* __restrict__ W1,
                                            const float* __restrict__ W2,
                                            unsigned short* __restrict__ B1h,
                                            unsigned short* __restrict__ B1l,
                                            unsigned short* __restrict__ B2h,
                                            unsigned short* __restrict__ B2l) {
    const int c = blockIdx.x;
    if (c < NCH) {
        __shared__ int h[NBKT];
        h[threadIdx.x] = 0;
        __syncthreads();
        const int e0 = c * epc;
        const int e1 = min(E, e0 + epc);
        for (int e = e0 + threadIdx.x; e < e1; e += 256)
            atomicAdd(&h[dst[e] >> 8], 1);
        __syncthreads();
        cnt[c * NBKT + threadIdx.x] = h[threadIdx.x];
        return;
    }
    // W split into MFMA fragment order
    int i = (c - NCH) * 256 + threadIdx.x;
    const float* W;
    unsigned short *Th, *Tl;
    int K, logM, idx;
    if (i < 32768) { W = W1; Th = B1h; Tl = B1l; K = 256; logM = 7; idx = i; }
    else if (i < 32768 + 8192) { W = W2; Th = B2h; Tl = B2l; K = 128; logM = 6; idx = i - 32768; }
    else return;
    const int M = 1 << logM;
    const int KS = K / 32;
    int k = idx >> logM;
    int n = idx & (M - 1);
    float v = W[idx];
    unsigned short h = f2bf(v);
    unsigned short l = f2bf(v - bf2f(h));
    int g = n >> 4, n16 = n & 15, ks = k >> 5, quad = (k >> 3) & 3, j = k & 7;
    size_t o = ((size_t)((g * KS + ks) * 64 + quad * 16 + n16)) * 8 + j;
    Th[o] = h;
    Tl[o] = l;
}

// S1: per-bucket exclusive scan over chunks; off[c][b], total[b]
__global__ __launch_bounds__(256) void bkt_scan_chunks(const int* __restrict__ cnt,
                                                       int* __restrict__ off,
                                                       int* __restrict__ total) {
    __shared__ int sh[256];
    const int b = blockIdx.x;
    const int t = threadIdx.x;
    int v = cnt[t * NBKT + b];
    sh[t] = v;
    __syncthreads();
    for (int o = 1; o < 256; o <<= 1) {
        int u = (t >= o) ? sh[t - o] : 0;
        __syncthreads();
        sh[t] += u;
        __syncthreads();
    }
    off[t * NBKT + b] = sh[t] - v;
    if (t == 255) total[b] = sh[255];
}

// B2: scatter packed (src<<8 | dst&255) into bucket-sorted order; LDS cursors.
__global__ __launch_bounds__(256) void bkt_scatter(const int* __restrict__ src,
                                                   const int* __restrict__ dst,
                                                   const int* __restrict__ off,
                                                   const int* __restrict__ total,
                                                   unsigned* __restrict__ pairs,
                                                   int E, int epc) {
    __shared__ int sh[256];
    __shared__ int cur[NBKT];
    const int c = blockIdx.x;
    const int t = threadIdx.x;
    int v = total[t];
    sh[t] = v;
    __syncthreads();
    for (int o = 1; o < 256; o <<= 1) {
        int u = (t >= o) ? sh[t - o] : 0;
        __syncthreads();
        sh[t] += u;
        __syncthreads();
    }
    cur[t] = (sh[t] - v) + off[c * NBKT + t];   // bbase[t] + off[c][t]
    __syncthreads();
    const int e0 = c * epc;
    const int e1 = min(E, e0 + epc);
    for (int e = e0 + t; e < e1; e += 256) {
        int s = src[e];
        int d = dst[e];
        int pos = atomicAdd(&cur[d >> 8], 1);
        pairs[pos] = ((unsigned)s << 8) | (unsigned)(d & 255);
    }
}

// B3: per-bucket local CSR: rowptr, dinv, csr_src (dense regional writes).
__global__ __launch_bounds__(256) void bkt_csr(const unsigned* __restrict__ pairs,
                                               const int* __restrict__ total,
                                               int* __restrict__ rowptr,
                                               int* __restrict__ csr_src,
                                               float* __restrict__ dinv, int N) {
    __shared__ int lh[256];
    __shared__ int sc[256];
    __shared__ int lcur[256];
    const int b = blockIdx.x;
    const int t = threadIdx.x;

    sc[t] = total[t];
    __syncthreads();
    for (int o = 1; o < 256; o <<= 1) {
        int u = (t >= o) ? sc[t - o] : 0;
        __syncthreads();
        sc[t] += u;
        __syncthreads();
    }
    const int eend = sc[b];
    const int ebase = eend - total[b];
    const int node0 = b << 8;

    lh[t] = 0;
    __syncthreads();
    for (int e = ebase + t; e < eend; e += 256)
        atomicAdd(&lh[pairs[e] & 255u], 1);
    __syncthreads();
    int v = lh[t];
    sc[t] = v;
    __syncthreads();
    for (int o = 1; o < 256; o <<= 1) {
        int u = (t >= o) ? sc[t - o] : 0;
        __syncthreads();
        sc[t] += u;
        __syncthreads();
    }
    const int excl = sc[t] - v;
    lcur[t] = ebase + excl;
    const int node = node0 + t;
    if (node <= N) {
        rowptr[node] = ebase + excl;            // node==N: rowptr[N]=E
        if (node < N) dinv[node] = rsqrtf((float)(v + 1));  // +1 self-loop
    }
    __syncthreads();
    for (int e = ebase + t; e < eend; e += 256) {
        unsigned p = pairs[e];
        int pos = atomicAdd(&lcur[p & 255u], 1);
        csr_src[pos] = (int)(p >> 8);
    }
}

// ============ MFMA GEMM (layer1): fp32 A -> 3-term split, 32x32/wave,
//              rolling B, dbuf LDS, bf16 monolithic out ============
template <int K, int M>
__global__ __launch_bounds__(M * 4) void gemm_mfma_v4(const float* __restrict__ A,
                                                      const unsigned short* __restrict__ Bfh,
                                                      const unsigned short* __restrict__ Bfl,
                                                      const float* __restrict__ dinv,
                                                      unsigned short* __restrict__ Cb, int N) {
    const int KS = K / 32;
    const int THREADS = M * 4;
    const int CPT = 512 / THREADS;
    const int PL = 64 * 40;
    const int CPAIRS = M / 32;

    __shared__ __align__(16) unsigned short Ah[2 * PL];
    __shared__ __align__(16) unsigned short Al[2 * PL];

    const int tid = threadIdx.x;
    const int wave = tid >> 6;
    const int lane = tid & 63;
    const int n16 = lane & 15;
    const int quad = lane >> 4;
    const int cpair = wave & (CPAIRS - 1);
    const int rpair = wave / CPAIRS;
    const int row0 = blockIdx.x * 64;

    bf16x8 bh[2][2], bl[2][2];
    auto loadB = [&](int ks, int par) {
#pragma unroll
        for (int ct = 0; ct < 2; ct++) {
            const int g = cpair * 2 + ct;
            const size_t o = ((size_t)(g * KS + ks) * 64 + lane) * 8;
            bh[par][ct] = *(const bf16x8*)(Bfh + o);
            bl[par][ct] = *(const bf16x8*)(Bfl + o);
        }
    };
    loadB(0, 0);

    int srow[CPT], sc4[CPT];
    const float* aptr[CPT];
#pragma unroll
    for (int p = 0; p < CPT; p++) {
        int q = p * THREADS + tid;
        srow[p] = q >> 3;
        sc4[p] = q & 7;
        int grow = row0 + srow[p];
        if (grow >= N) grow = N - 1;
        aptr[p] = A + (size_t)grow * K + sc4[p] * 4;
    }

    float4 pre[CPT];
#pragma unroll
    for (int p = 0; p < CPT; p++) pre[p] = *(const float4*)(aptr[p]);

#pragma unroll
    for (int p = 0; p < CPT; p++) {
        ushort4 h4, l4;
        unsigned short* hp = (unsigned short*)&h4;
        unsigned short* lp = (unsigned short*)&l4;
        float av[4] = {pre[p].x, pre[p].y, pre[p].z, pre[p].w};
#pragma unroll
        for (int j = 0; j < 4; j++) {
            unsigned short h = f2bf(av[j]);
            hp[j] = h;
            lp[j] = f2bf(av[j] - bf2f(h));
        }
        *(ushort4*)(Ah + srow[p] * 40 + sc4[p] * 4) = h4;
        *(ushort4*)(Al + srow[p] * 40 + sc4[p] * 4) = l4;
    }
    if (KS > 1) {
#pragma unroll
        for (int p = 0; p < CPT; p++) pre[p] = *(const float4*)(aptr[p] + 32);
    }
    __syncthreads();

    f32x4 acc[2][2] = {};

#pragma unroll
    for (int ks = 0; ks < KS; ks++) {
        const int cur = ks & 1;
        if (ks + 1 < KS) loadB(ks + 1, cur ^ 1);
#pragma unroll
        for (int rt = 0; rt < 2; rt++) {
            const int ro = cur * PL + (rpair * 32 + rt * 16 + n16) * 40 + quad * 8;
            bf16x8 ah = *(const bf16x8*)(Ah + ro);
            bf16x8 al = *(const bf16x8*)(Al + ro);
#pragma unroll
            for (int ct = 0; ct < 2; ct++) {
                acc[rt][ct] = __builtin_amdgcn_mfma_f32_16x16x32_bf16(ah, bh[cur][ct], acc[rt][ct], 0, 0, 0);
                acc[rt][ct] = __builtin_amdgcn_mfma_f32_16x16x32_bf16(ah, bl[cur][ct], acc[rt][ct], 0, 0, 0);
                acc[rt][ct] = __builtin_amdgcn_mfma_f32_16x16x32_bf16(al, bh[cur][ct], acc[rt][ct], 0, 0, 0);
            }
        }
        if (ks + 1 < KS) {
            const int nxt = (cur ^ 1) * PL;
#pragma unroll
            for (int p = 0; p < CPT; p++) {
                ushort4 h4, l4;
                unsigned short* hp = (unsigned short*)&h4;
                unsigned short* lp = (unsigned short*)&l4;
                float av[4] = {pre[p].x, pre[p].y, pre[p].z, pre[p].w};
#pragma unroll
                for (int j = 0; j < 4; j++) {
                    unsigned short h = f2bf(av[j]);
                    hp[j] = h;
                    lp[j] = f2bf(av[j] - bf2f(h));
                }
                *(ushort4*)(Ah + nxt + srow[p] * 40 + sc4[p] * 4) = h4;
                *(ushort4*)(Al + nxt + srow[p] * 40 + sc4[p] * 4) = l4;
            }
            if (ks + 2 < KS) {
#pragma unroll
                for (int p = 0; p < CPT; p++)
                    pre[p] = *(const float4*)(aptr[p] + (ks + 2) * 32);
            }
        }
        __syncthreads();
    }

#pragma unroll
    for (int rt = 0; rt < 2; rt++) {
#pragma unroll
        for (int ct = 0; ct < 2; ct++) {
            const int col = cpair * 32 + ct * 16 + n16;
            const int rbase = row0 + rpair * 32 + rt * 16 + quad * 4;
#pragma unroll
            for (int r = 0; r < 4; r++) {
                int orow = rbase + r;
                if (orow < N) {
                    Cb[(size_t)orow * M + col] = f2bf(dinv[orow] * acc[rt][ct][r]);
                }
            }
        }
    }
}

// ============ FUSED: gather1(+ReLU+bias) -> LDS A-tile -> GEMM layer2 ============
// 1024 threads: phase 1 is one (node, 8-col-slice) per thread (16 slices x 64 rows).
// Edge loop: 8-edge unrolled (two exact 4-groups -> bit-identical summation) with
// index prefetch, doubling in-flight row loads per wave (MLP/latency attack).
// After the barrier, waves 0-3 run the resident-A GEMM; waves 4-15 exit.
template <int K, int M>   // K=128 (h1 cols), M=64 (out cols)
__global__ __launch_bounds__(1024) void gather_gemm2(const unsigned short* __restrict__ hnb,
                                                     const int* __restrict__ rowptr,
                                                     const int* __restrict__ csr_src,
                                                     const float* __restrict__ dinv,
                                                     const float* __restrict__ bias,
                                                     const unsigned short* __restrict__ Bfh,
                                                     const unsigned short* __restrict__ Bfl,
                                                     unsigned short* __restrict__ Cb, int N) {
    const int KS = K / 32;          // 4
    const int CPAIRS = M / 32;      // 2
    const int PLP = 64 * 40;        // panel elems (64 rows x 32 cols, stride 40)

    __shared__ __align__(16) unsigned short Ah[KS * PLP];   // 20 KB

    const int tid = threadIdx.x;
    const int wave = tid >> 6;
    const int lane = tid & 63;
    const int n16 = lane & 15;
    const int quad = lane >> 4;
    const int cpair = wave & (CPAIRS - 1);
    const int rpair = (wave / CPAIRS) & 1;   // only valid for waves 0-3
    const int row0 = blockIdx.x * 64;

    bf16x8 bh[2][2], bl[2][2];
    auto loadB = [&](int ks, int par) {
#pragma unroll
        for (int ct = 0; ct < 2; ct++) {
            const int g = cpair * 2 + ct;
            const size_t o = ((size_t)(g * KS + ks) * 64 + lane) * 8;
            bh[par][ct] = *(const bf16x8*)(Bfh + o);
            bl[par][ct] = *(const bf16x8*)(Bfl + o);
        }
    };
    if (wave < 4) loadB(0, 0);   // in flight during the gather phase

    // ---- phase 1: aggregate 64 nodes into LDS panels (MFMA A layout) ----
    {
        const int j = tid & 15;      // 8-col slice, K/8 = 16 slices
        const int r = tid >> 4;      // node-local row, [0,64)
        const int panel = j >> 2;
        const int coff = (j & 3) * 8;
        const int g = row0 + r;
        unsigned short* ldst = Ah + panel * PLP + r * 40 + coff;
        if (g < N) {
            float acc[8];
            {
                bf16x8 v = *(const bf16x8*)(hnb + (size_t)g * K + j * 8);  // self-loop
#pragma unroll
                for (int i = 0; i < 8; i++) acc[i] = bf2f((unsigned short)v[i]);
            }
            int e = rowptr[g];
            const int end = rowptr[g + 1];

            // 8-edge unroll with index prefetch (two 4-groups -> exact order)
            int idx[8];
            if (e + 7 < end) {
#pragma unroll
                for (int i = 0; i < 8; i++) idx[i] = csr_src[e + i];
            }
            while (e + 7 < end) {
                int cur[8];
#pragma unroll
                for (int i = 0; i < 8; i++) cur[i] = idx[i];
                const int en = e + 8;
                if (en + 7 < end) {
#pragma unroll
                    for (int i = 0; i < 8; i++) idx[i] = csr_src[en + i];
                }
                bf16x8 v[8];
#pragma unroll
                for (int i = 0; i < 8; i++)
                    v[i] = *(const bf16x8*)(hnb + (size_t)cur[i] * K + j * 8);
#pragma unroll
                for (int q = 0; q < 2; q++) {
#pragma unroll
                    for (int i = 0; i < 8; i++) {
                        acc[i] += (bf2f((unsigned short)v[q * 4 + 0][i]) + bf2f((unsigned short)v[q * 4 + 1][i])) +
                                  (bf2f((unsigned short)v[q * 4 + 2][i]) + bf2f((unsigned short)v[q * 4 + 3][i]));
                    }
                }
                e = en;
            }
            for (; e + 3 < end; e += 4) {
                int s0 = csr_src[e];
                int s1 = csr_src[e + 1];
                int s2 = csr_src[e + 2];
                int s3 = csr_src[e + 3];
                bf16x8 v0 = *(const bf16x8*)(hnb + (size_t)s0 * K + j * 8);
                bf16x8 v1 = *(const bf16x8*)(hnb + (size_t)s1 * K + j * 8);
                bf16x8 v2 = *(const bf16x8*)(hnb + (size_t)s2 * K + j * 8);
                bf16x8 v3 = *(const bf16x8*)(hnb + (size_t)s3 * K + j * 8);
#pragma unroll
                for (int i = 0; i < 8; i++) {
                    acc[i] += (bf2f((unsigned short)v0[i]) + bf2f((unsigned short)v1[i])) +
                              (bf2f((unsigned short)v2[i]) + bf2f((unsigned short)v3[i]));
                }
            }
            for (; e < end; e++) {
                int s0 = csr_src[e];
                bf16x8 v0 = *(const bf16x8*)(hnb + (size_t)s0 * K + j * 8);
#pragma unroll
                for (int i = 0; i < 8; i++) acc[i] += bf2f((unsigned short)v0[i]);
            }
            const float s = dinv[g];
            bf16x8 rr;
#pragma unroll
            for (int i = 0; i < 8; i++)
                rr[i] = (short)f2bf(fmaxf(s * acc[i] + bias[j * 8 + i], 0.0f));  // ReLU
            *(bf16x8*)ldst = rr;
        } else {
            bf16x8 z = {};
            *(bf16x8*)ldst = z;
        }
    }
    __syncthreads();
    if (wave >= 4) return;   // gather-only waves done; no further barriers below

    // ---- phase 2: GEMM over resident A-tile (waves 0-3) ----
    f32x4 acc[2][2] = {};
#pragma unroll
    for (int ks = 0; ks < KS; ks++) {
        const int cur = ks & 1;
        if (ks + 1 < KS) loadB(ks + 1, cur ^ 1);
#pragma unroll
        for (int rt = 0; rt < 2; rt++) {
            const int ro = ks * PLP + (rpair * 32 + rt * 16 + n16) * 40 + quad * 8;
            bf16x8 ah = *(const bf16x8*)(Ah + ro);
#pragma unroll
            for (int ct = 0; ct < 2; ct++) {
                acc[rt][ct] = __builtin_amdgcn_mfma_f32_16x16x32_bf16(ah, bh[cur][ct], acc[rt][ct], 0, 0, 0);
                acc[rt][ct] = __builtin_amdgcn_mfma_f32_16x16x32_bf16(ah, bl[cur][ct], acc[rt][ct], 0, 0, 0);
            }
        }
    }

#pragma unroll
    for (int rt = 0; rt < 2; rt++) {
#pragma unroll
        for (int ct = 0; ct < 2; ct++) {
            const int col = cpair * 32 + ct * 16 + n16;
            const int rbase = row0 + rpair * 32 + rt * 16 + quad * 4;
#pragma unroll
            for (int r = 0; r < 4; r++) {
                int orow = rbase + r;
                if (orow < N) {
                    Cb[(size_t)orow * M + col] = f2bf(dinv[orow] * acc[rt][ct][r]);
                }
            }
        }
    }
}

// ============ gather-aggregate (bf16 rows in) -> fp32 out (no ReLU) ============
// Same 8-edge unroll + index prefetch as gg2 phase 1.
template <int M>
__global__ __launch_bounds__(256) void gather_to_f32(const unsigned short* __restrict__ hnb,
                                                     const int* __restrict__ rowptr,
                                                     const int* __restrict__ csr_src,
                                                     const float* __restrict__ dinv,
                                                     const float* __restrict__ bias,
                                                     float* __restrict__ outp, int n) {
    const int MQ = M / 8;
    const int GPB = 256 / MQ;
    int g = blockIdx.x * GPB + threadIdx.x / MQ;
    int j = threadIdx.x % MQ;
    if (g >= n) return;

    float acc[8];
    {
        bf16x8 v = *(const bf16x8*)(hnb + (size_t)g * M + j * 8);  // self-loop
#pragma unroll
        for (int i = 0; i < 8; i++) acc[i] = bf2f((unsigned short)v[i]);
    }

    int e = rowptr[g];
    const int end = rowptr[g + 1];

    int idx[8];
    if (e + 7 < end) {
#pragma unroll
        for (int i = 0; i < 8; i++) idx[i] = csr_src[e + i];
    }
    while (e + 7 < end) {
        int cur[8];
#pragma unroll
        for (int i = 0; i < 8; i++) cur[i] = idx[i];
        const int en = e + 8;
        if (en + 7 < end) {
#pragma unroll
            for (int i = 0; i < 8; i++) idx[i] = csr_src[en + i];
        }
        bf16x8 v[8];
#pragma unroll
        for (int i = 0; i < 8; i++)
            v[i] = *(const bf16x8*)(hnb + (size_t)cur[i] * M + j * 8);
#pragma unroll
        for (int q = 0; q < 2; q++) {
#pragma unroll
            for (int i = 0; i < 8; i++) {
                acc[i] += (bf2f((unsigned short)v[q * 4 + 0][i]) + bf2f((unsigned short)v[q * 4 + 1][i])) +
                          (bf2f((unsigned short)v[q * 4 + 2][i]) + bf2f((unsigned short)v[q * 4 + 3][i]));
            }
        }
        e = en;
    }
    for (; e + 3 < end; e += 4) {
        int s0 = csr_src[e];
        int s1 = csr_src[e + 1];
        int s2 = csr_src[e + 2];
        int s3 = csr_src[e + 3];
        bf16x8 v0 = *(const bf16x8*)(hnb + (size_t)s0 * M + j * 8);
        bf16x8 v1 = *(const bf16x8*)(hnb + (size_t)s1 * M + j * 8);
        bf16x8 v2 = *(const bf16x8*)(hnb + (size_t)s2 * M + j * 8);
        bf16x8 v3 = *(const bf16x8*)(hnb + (size_t)s3 * M + j * 8);
#pragma unroll
        for (int i = 0; i < 8; i++) {
            acc[i] += (bf2f((unsigned short)v0[i]) + bf2f((unsigned short)v1[i])) +
                      (bf2f((unsigned short)v2[i]) + bf2f((unsigned short)v3[i]));
        }
    }
    for (; e < end; e++) {
        int s0 = csr_src[e];
        bf16x8 v0 = *(const bf16x8*)(hnb + (size_t)s0 * M + j * 8);
#pragma unroll
        for (int i = 0; i < 8; i++) acc[i] += bf2f((unsigned short)v0[i]);
    }

    const float s = dinv[g];
    float r[8];
#pragma unroll
    for (int i = 0; i < 8; i++) r[i] = s * acc[i] + bias[j * 8 + i];
    float* op = outp + (size_t)g * M + j * 8;
    *(float4*)(op) = make_float4(r[0], r[1], r[2], r[3]);
    *(float4*)(op + 4) = make_float4(r[4], r[5], r[6], r[7]);
}

extern "C" void kernel_launch(void* const* d_in, const int* in_sizes, int n_in,
                              void* d_out, int out_size, void* d_ws, size_t ws_size,
                              hipStream_t stream) {
    const float* x  = (const float*)d_in[0];
    const int*   ei = (const int*)d_in[1];
    const float* W1 = (const float*)d_in[2];
    const float* b1 = (const float*)d_in[3];
    const float* W2 = (const float*)d_in[4];
    const float* b2 = (const float*)d_in[5];

    const int N = N_NODES;
    const int E = in_sizes[1] / 2;
    const int* src = ei;
    const int* dst = ei + E;

    char* ws = (char*)d_ws;
    size_t off = 0;
    auto carve = [&](size_t bytes) {
        char* p = ws + off;
        off += (bytes + 255) & ~(size_t)255;
        return p;
    };
    int*      cnt     = (int*)     carve((size_t)NCH * NBKT * 4);
    int*      offm    = (int*)     carve((size_t)NCH * NBKT * 4);
    int*      total   = (int*)     carve((size_t)NBKT * 4);
    unsigned* pairs   = (unsigned*)carve((size_t)E * 4);
    int*      rowptr  = (int*)     carve((size_t)(N + 1) * 4);
    int*      csr_src = (int*)     carve((size_t)E * 4);
    float*    dinv    = (float*)   carve((size_t)N * 4);
    unsigned short* W1th = (unsigned short*)carve((size_t)256 * 128 * 2);
    unsigned short* W1tl = (unsigned short*)carve((size_t)256 * 128 * 2);
    unsigned short* W2th = (unsigned short*)carve((size_t)128 * 64 * 2);
    unsigned short* W2tl = (unsigned short*)carve((size_t)128 * 64 * 2);
    unsigned short* hn1b = (unsigned short*)carve((size_t)N * 128 * 2);  // bf16
    unsigned short* hn2b = (unsigned short*)carve((size_t)N * 64 * 2);   // bf16

    const int epc = (E + NCH - 1) / NCH;
    const int nbk = (N + 255) >> 8;  // 196 live buckets

    // ---- CSR build + weight split ----
    prep<<<NCH + 160, 256, 0, stream>>>(dst, cnt, E, epc, W1, W2, W1th, W1tl, W2th, W2tl);
    bkt_scan_chunks<<<NBKT, 256, 0, stream>>>(cnt, offm, total);
    bkt_scatter<<<NCH, 256, 0, stream>>>(src, dst, offm, total, pairs, E, epc);
    bkt_csr<<<nbk, 256, 0, stream>>>(pairs, total, rowptr, csr_src, dinv, N);

    const int GB = (N + 63) / 64;  // 782 blocks

    // ---- layer 1 transform ----
    gemm_mfma_v4<256, 128><<<GB, 512, 0, stream>>>(x, W1th, W1tl, dinv, hn1b, N);

    // ---- layer 1 aggregate + ReLU fused with layer 2 transform (16 waves/block) ----
    gather_gemm2<128, 64><<<GB, 1024, 0, stream>>>(hn1b, rowptr, csr_src, dinv, b1,
                                                   W2th, W2tl, hn2b, N);

    // ---- layer 2 aggregate -> fp32 out ----
    {
        const int GPB = 256 / (64 / 8);  // 32 nodes/block
        gather_to_f32<64><<<(N + GPB - 1) / GPB, 256, 0, stream>>>(
            hn2b, rowptr, csr_src, dinv, b2, (float*)d_out, N);
    }
}

// Round 7
// 207.374 us; speedup vs baseline: 1.0683x; 1.0039x over previous
//
#include <hip/hip_runtime.h>

#define N_NODES 50000
#define NCH 256          // edge chunks (blocks in count/scatter)
#define NBKT 256         // bucket slots (dst>>8; 196 live for N=50000)

typedef short bf16x8 __attribute__((ext_vector_type(8)));
typedef float f32x4 __attribute__((ext_vector_type(4)));

__device__ inline unsigned short f2bf(float f) {
    union { float f; unsigned u; } v; v.f = f;
    unsigned u = v.u;
    unsigned lsb = (u >> 16) & 1u;
    u += 0x7fffu + lsb;  // round-to-nearest-even
    return (unsigned short)(u >> 16);
}

__device__ inline float bf2f(unsigned short h) {
    union { unsigned u; float f; } v; v.u = ((unsigned)h) << 16;
    return v.f;
}

// ============ prep: bucket histogram (blocks < NCH) + W split (blocks >= NCH) ============
__global__ __launch_bounds__(256) void prep(const int* __restrict__ dst,
                                            int* __restrict__ cnt, int E, int epc,
                                            const float* __restrict__ W1,
                                            const float* __restrict__ W2,
                                            unsigned short* __restrict__ B1h,
                                            unsigned short* __restrict__ B1l,
                                            unsigned short* __restrict__ B2h,
                                            unsigned short* __restrict__ B2l) {
    const int c = blockIdx.x;
    if (c < NCH) {
        __shared__ int h[NBKT];
        h[threadIdx.x] = 0;
        __syncthreads();
        const int e0 = c * epc;
        const int e1 = min(E, e0 + epc);
        for (int e = e0 + threadIdx.x; e < e1; e += 256)
            atomicAdd(&h[dst[e] >> 8], 1);
        __syncthreads();
        cnt[c * NBKT + threadIdx.x] = h[threadIdx.x];
        return;
    }
    // W split into MFMA fragment order
    int i = (c - NCH) * 256 + threadIdx.x;
    const float* W;
    unsigned short *Th, *Tl;
    int K, logM, idx;
    if (i < 32768) { W = W1; Th = B1h; Tl = B1l; K = 256; logM = 7; idx = i; }
    else if (i < 32768 + 8192) { W = W2; Th = B2h; Tl = B2l; K = 128; logM = 6; idx = i - 32768; }
    else return;
    const int M = 1 << logM;
    const int KS = K / 32;
    int k = idx >> logM;
    int n = idx & (M - 1);
    float v = W[idx];
    unsigned short h = f2bf(v);
    unsigned short l = f2bf(v - bf2f(h));
    int g = n >> 4, n16 = n & 15, ks = k >> 5, quad = (k >> 3) & 3, j = k & 7;
    size_t o = ((size_t)((g * KS + ks) * 64 + quad * 16 + n16)) * 8 + j;
    Th[o] = h;
    Tl[o] = l;
}

// S1: per-bucket exclusive scan over chunks; off[c][b], total[b]
__global__ __launch_bounds__(256) void bkt_scan_chunks(const int* __restrict__ cnt,
                                                       int* __restrict__ off,
                                                       int* __restrict__ total) {
    __shared__ int sh[256];
    const int b = blockIdx.x;
    const int t = threadIdx.x;
    int v = cnt[t * NBKT + b];
    sh[t] = v;
    __syncthreads();
    for (int o = 1; o < 256; o <<= 1) {
        int u = (t >= o) ? sh[t - o] : 0;
        __syncthreads();
        sh[t] += u;
        __syncthreads();
    }
    off[t * NBKT + b] = sh[t] - v;
    if (t == 255) total[b] = sh[255];
}

// B2: scatter packed (src<<8 | dst&255) into bucket-sorted order; LDS cursors.
__global__ __launch_bounds__(256) void bkt_scatter(const int* __restrict__ src,
                                                   const int* __restrict__ dst,
                                                   const int* __restrict__ off,
                                                   const int* __restrict__ total,
                                                   unsigned* __restrict__ pairs,
                                                   int E, int epc) {
    __shared__ int sh[256];
    __shared__ int cur[NBKT];
    const int c = blockIdx.x;
    const int t = threadIdx.x;
    int v = total[t];
    sh[t] = v;
    __syncthreads();
    for (int o = 1; o < 256; o <<= 1) {
        int u = (t >= o) ? sh[t - o] : 0;
        __syncthreads();
        sh[t] += u;
        __syncthreads();
    }
    cur[t] = (sh[t] - v) + off[c * NBKT + t];   // bbase[t] + off[c][t]
    __syncthreads();
    const int e0 = c * epc;
    const int e1 = min(E, e0 + epc);
    for (int e = e0 + t; e < e1; e += 256) {
        int s = src[e];
        int d = dst[e];
        int pos = atomicAdd(&cur[d >> 8], 1);
        pairs[pos] = ((unsigned)s << 8) | (unsigned)(d & 255);
    }
}

// B3: per-bucket local CSR: rowptr, dinv, csr_src (dense regional writes).
__global__ __launch_bounds__(256) void bkt_csr(const unsigned* __restrict__ pairs,
                                               const int* __restrict__ total,
                                               int* __restrict__ rowptr,
                                               int* __restrict__ csr_src,
                                               float* __restrict__ dinv, int N) {
    __shared__ int lh[256];
    __shared__ int sc[256];
    __shared__ int lcur[256];
    const int b = blockIdx.x;
    const int t = threadIdx.x;

    sc[t] = total[t];
    __syncthreads();
    for (int o = 1; o < 256; o <<= 1) {
        int u = (t >= o) ? sc[t - o] : 0;
        __syncthreads();
        sc[t] += u;
        __syncthreads();
    }
    const int eend = sc[b];
    const int ebase = eend - total[b];
    const int node0 = b << 8;

    lh[t] = 0;
    __syncthreads();
    for (int e = ebase + t; e < eend; e += 256)
        atomicAdd(&lh[pairs[e] & 255u], 1);
    __syncthreads();
    int v = lh[t];
    sc[t] = v;
    __syncthreads();
    for (int o = 1; o < 256; o <<= 1) {
        int u = (t >= o) ? sc[t - o] : 0;
        __syncthreads();
        sc[t] += u;
        __syncthreads();
    }
    const int excl = sc[t] - v;
    lcur[t] = ebase + excl;
    const int node = node0 + t;
    if (node <= N) {
        rowptr[node] = ebase + excl;            // node==N: rowptr[N]=E
        if (node < N) dinv[node] = rsqrtf((float)(v + 1));  // +1 self-loop
    }
    __syncthreads();
    for (int e = ebase + t; e < eend; e += 256) {
        unsigned p = pairs[e];
        int pos = atomicAdd(&lcur[p & 255u], 1);
        csr_src[pos] = (int)(p >> 8);
    }
}

// ============ MFMA GEMM (layer1): fp32 A -> 3-term split, 32x32/wave,
//              rolling B, dbuf LDS; PLANAR out: 4 planes of [N][32] bf16 ============
template <int K, int M>
__global__ __launch_bounds__(M * 4) void gemm_mfma_v4(const float* __restrict__ A,
                                                      const unsigned short* __restrict__ Bfh,
                                                      const unsigned short* __restrict__ Bfl,
                                                      const float* __restrict__ dinv,
                                                      unsigned short* __restrict__ Cb, int N) {
    const int KS = K / 32;
    const int THREADS = M * 4;
    const int CPT = 512 / THREADS;
    const int PL = 64 * 40;
    const int CPAIRS = M / 32;

    __shared__ __align__(16) unsigned short Ah[2 * PL];
    __shared__ __align__(16) unsigned short Al[2 * PL];

    const int tid = threadIdx.x;
    const int wave = tid >> 6;
    const int lane = tid & 63;
    const int n16 = lane & 15;
    const int quad = lane >> 4;
    const int cpair = wave & (CPAIRS - 1);
    const int rpair = wave / CPAIRS;
    const int row0 = blockIdx.x * 64;

    bf16x8 bh[2][2], bl[2][2];
    auto loadB = [&](int ks, int par) {
#pragma unroll
        for (int ct = 0; ct < 2; ct++) {
            const int g = cpair * 2 + ct;
            const size_t o = ((size_t)(g * KS + ks) * 64 + lane) * 8;
            bh[par][ct] = *(const bf16x8*)(Bfh + o);
            bl[par][ct] = *(const bf16x8*)(Bfl + o);
        }
    };
    loadB(0, 0);

    int srow[CPT], sc4[CPT];
    const float* aptr[CPT];
#pragma unroll
    for (int p = 0; p < CPT; p++) {
        int q = p * THREADS + tid;
        srow[p] = q >> 3;
        sc4[p] = q & 7;
        int grow = row0 + srow[p];
        if (grow >= N) grow = N - 1;
        aptr[p] = A + (size_t)grow * K + sc4[p] * 4;
    }

    float4 pre[CPT];
#pragma unroll
    for (int p = 0; p < CPT; p++) pre[p] = *(const float4*)(aptr[p]);

#pragma unroll
    for (int p = 0; p < CPT; p++) {
        ushort4 h4, l4;
        unsigned short* hp = (unsigned short*)&h4;
        unsigned short* lp = (unsigned short*)&l4;
        float av[4] = {pre[p].x, pre[p].y, pre[p].z, pre[p].w};
#pragma unroll
        for (int j = 0; j < 4; j++) {
            unsigned short h = f2bf(av[j]);
            hp[j] = h;
            lp[j] = f2bf(av[j] - bf2f(h));
        }
        *(ushort4*)(Ah + srow[p] * 40 + sc4[p] * 4) = h4;
        *(ushort4*)(Al + srow[p] * 40 + sc4[p] * 4) = l4;
    }
    if (KS > 1) {
#pragma unroll
        for (int p = 0; p < CPT; p++) pre[p] = *(const float4*)(aptr[p] + 32);
    }
    __syncthreads();

    f32x4 acc[2][2] = {};

#pragma unroll
    for (int ks = 0; ks < KS; ks++) {
        const int cur = ks & 1;
        if (ks + 1 < KS) loadB(ks + 1, cur ^ 1);
#pragma unroll
        for (int rt = 0; rt < 2; rt++) {
            const int ro = cur * PL + (rpair * 32 + rt * 16 + n16) * 40 + quad * 8;
            bf16x8 ah = *(const bf16x8*)(Ah + ro);
            bf16x8 al = *(const bf16x8*)(Al + ro);
#pragma unroll
            for (int ct = 0; ct < 2; ct++) {
                acc[rt][ct] = __builtin_amdgcn_mfma_f32_16x16x32_bf16(ah, bh[cur][ct], acc[rt][ct], 0, 0, 0);
                acc[rt][ct] = __builtin_amdgcn_mfma_f32_16x16x32_bf16(ah, bl[cur][ct], acc[rt][ct], 0, 0, 0);
                acc[rt][ct] = __builtin_amdgcn_mfma_f32_16x16x32_bf16(al, bh[cur][ct], acc[rt][ct], 0, 0, 0);
            }
        }
        if (ks + 1 < KS) {
            const int nxt = (cur ^ 1) * PL;
#pragma unroll
            for (int p = 0; p < CPT; p++) {
                ushort4 h4, l4;
                unsigned short* hp = (unsigned short*)&h4;
                unsigned short* lp = (unsigned short*)&l4;
                float av[4] = {pre[p].x, pre[p].y, pre[p].z, pre[p].w};
#pragma unroll
                for (int j = 0; j < 4; j++) {
                    unsigned short h = f2bf(av[j]);
                    hp[j] = h;
                    lp[j] = f2bf(av[j] - bf2f(h));
                }
                *(ushort4*)(Ah + nxt + srow[p] * 40 + sc4[p] * 4) = h4;
                *(ushort4*)(Al + nxt + srow[p] * 40 + sc4[p] * 4) = l4;
            }
            if (ks + 2 < KS) {
#pragma unroll
                for (int p = 0; p < CPT; p++)
                    pre[p] = *(const float4*)(aptr[p] + (ks + 2) * 32);
            }
        }
        __syncthreads();
    }

#pragma unroll
    for (int rt = 0; rt < 2; rt++) {
#pragma unroll
        for (int ct = 0; ct < 2; ct++) {
            const int col = cpair * 32 + ct * 16 + n16;
            const int rbase = row0 + rpair * 32 + rt * 16 + quad * 4;
#pragma unroll
            for (int r = 0; r < 4; r++) {
                int orow = rbase + r;
                if (orow < N) {
                    unsigned short ob = f2bf(dinv[orow] * acc[rt][ct][r]);
                    Cb[(size_t)(col >> 5) * ((size_t)N_NODES * 32) +
                       (size_t)orow * 32 + (col & 31)] = ob;
                }
            }
        }
    }
}

// ============ gather1 (XCD channel-quarter partition) ============
// grid = 4*GB; q = blockIdx&3 selects channel quarter [32q,32q+32).
// Dispatch round-robin pins quarter q to XCDs {q, q+4}: each XCD's random
// working set = N*64B = 3.2 MB < 4 MiB L2 -> row re-reads become L2 hits.
// 256 thr = 64 rows x 4 slices. Planar in (4x[N][32]) -> planar out (same).
__global__ __launch_bounds__(256) void gather1_xcd(const unsigned short* __restrict__ hnb,
                                                   const int* __restrict__ rowptr,
                                                   const int* __restrict__ csr_src,
                                                   const float* __restrict__ dinv,
                                                   const float* __restrict__ bias,
                                                   unsigned short* __restrict__ outp,
                                                   int N) {
    const size_t PL = (size_t)N_NODES * 32;
    const int q = blockIdx.x & 3;
    const int tile = blockIdx.x >> 2;
    const int j = threadIdx.x & 3;    // 8-ch slice within quarter
    const int r = threadIdx.x >> 2;   // row 0..63
    const int g = tile * 64 + r;
    if (g >= N) return;

    const unsigned short* plane = hnb + (size_t)q * PL + j * 8;
    float acc[8];
    {
        bf16x8 v = *(const bf16x8*)(plane + (size_t)g * 32);  // self-loop
#pragma unroll
        for (int i = 0; i < 8; i++) acc[i] = bf2f((unsigned short)v[i]);
    }
    int e = rowptr[g];
    const int end = rowptr[g + 1];
    for (; e + 3 < end; e += 4) {
        int s0 = csr_src[e];
        int s1 = csr_src[e + 1];
        int s2 = csr_src[e + 2];
        int s3 = csr_src[e + 3];
        bf16x8 v0 = *(const bf16x8*)(plane + (size_t)s0 * 32);
        bf16x8 v1 = *(const bf16x8*)(plane + (size_t)s1 * 32);
        bf16x8 v2 = *(const bf16x8*)(plane + (size_t)s2 * 32);
        bf16x8 v3 = *(const bf16x8*)(plane + (size_t)s3 * 32);
#pragma unroll
        for (int i = 0; i < 8; i++) {
            acc[i] += (bf2f((unsigned short)v0[i]) + bf2f((unsigned short)v1[i])) +
                      (bf2f((unsigned short)v2[i]) + bf2f((unsigned short)v3[i]));
        }
    }
    for (; e < end; e++) {
        int s0 = csr_src[e];
        bf16x8 v0 = *(const bf16x8*)(plane + (size_t)s0 * 32);
#pragma unroll
        for (int i = 0; i < 8; i++) acc[i] += bf2f((unsigned short)v0[i]);
    }

    const float s = dinv[g];
    bf16x8 rr;
#pragma unroll
    for (int i = 0; i < 8; i++)
        rr[i] = (short)f2bf(fmaxf(s * acc[i] + bias[q * 32 + j * 8 + i], 0.0f));  // ReLU
    *(bf16x8*)(outp + (size_t)q * PL + (size_t)g * 32 + j * 8) = rr;
}

// ============ MFMA GEMM (layer2): bf16 A (PLANAR 4x[N][32]) direct-stage ============
template <int K, int M>
__global__ __launch_bounds__(M * 4) void gemm_mfma_bfA(const unsigned short* __restrict__ A,
                                                       const unsigned short* __restrict__ Bfh,
                                                       const unsigned short* __restrict__ Bfl,
                                                       const float* __restrict__ dinv,
                                                       unsigned short* __restrict__ Cb, int N) {
    const int KS = K / 32;
    const int PL = 64 * 40;
    const int CPAIRS = M / 32;
    const size_t APL = (size_t)N_NODES * 32;   // A plane stride

    __shared__ __align__(16) unsigned short Ah[2 * PL];

    const int tid = threadIdx.x;
    const int wave = tid >> 6;
    const int lane = tid & 63;
    const int n16 = lane & 15;
    const int quad = lane >> 4;
    const int cpair = wave & (CPAIRS - 1);
    const int rpair = wave / CPAIRS;
    const int row0 = blockIdx.x * 64;

    bf16x8 bh[2][2], bl[2][2];
    auto loadB = [&](int ks, int par) {
#pragma unroll
        for (int ct = 0; ct < 2; ct++) {
            const int g = cpair * 2 + ct;
            const size_t o = ((size_t)(g * KS + ks) * 64 + lane) * 8;
            bh[par][ct] = *(const bf16x8*)(Bfh + o);
            bl[par][ct] = *(const bf16x8*)(Bfl + o);
        }
    };
    loadB(0, 0);

    // A staging: 64 rows x 32 cols bf16 per ks; plane ks of planar A.
    const int srow = tid >> 2;
    const int sc8 = tid & 3;
    const unsigned short* aptr;
    {
        int grow = row0 + srow;
        if (grow >= N) grow = N - 1;
        aptr = A + (size_t)grow * 32 + sc8 * 8;
    }

    bf16x8 pre = *(const bf16x8*)(aptr);   // plane 0

    {
        ushort4* d0 = (ushort4*)(Ah + srow * 40 + sc8 * 8);
        ushort4 lo, hi;
        unsigned short* lp = (unsigned short*)&lo;
        unsigned short* hp = (unsigned short*)&hi;
#pragma unroll
        for (int j = 0; j < 4; j++) { lp[j] = (unsigned short)pre[j]; hp[j] = (unsigned short)pre[j + 4]; }
        d0[0] = lo;
        d0[1] = hi;
    }
    if (KS > 1) pre = *(const bf16x8*)(aptr + APL);   // plane 1
    __syncthreads();

    f32x4 acc[2][2] = {};

#pragma unroll
    for (int ks = 0; ks < KS; ks++) {
        const int cur = ks & 1;
        if (ks + 1 < KS) loadB(ks + 1, cur ^ 1);
#pragma unroll
        for (int rt = 0; rt < 2; rt++) {
            const int ro = cur * PL + (rpair * 32 + rt * 16 + n16) * 40 + quad * 8;
            bf16x8 ah = *(const bf16x8*)(Ah + ro);
#pragma unroll
            for (int ct = 0; ct < 2; ct++) {
                acc[rt][ct] = __builtin_amdgcn_mfma_f32_16x16x32_bf16(ah, bh[cur][ct], acc[rt][ct], 0, 0, 0);
                acc[rt][ct] = __builtin_amdgcn_mfma_f32_16x16x32_bf16(ah, bl[cur][ct], acc[rt][ct], 0, 0, 0);
            }
        }
        if (ks + 1 < KS) {
            const int nxt = (cur ^ 1) * PL;
            ushort4* d0 = (ushort4*)(Ah + nxt + srow * 40 + sc8 * 8);
            ushort4 lo, hi;
            unsigned short* lp = (unsigned short*)&lo;
            unsigned short* hp = (unsigned short*)&hi;
#pragma unroll
            for (int j = 0; j < 4; j++) { lp[j] = (unsigned short)pre[j]; hp[j] = (unsigned short)pre[j + 4]; }
            d0[0] = lo;
            d0[1] = hi;
            if (ks + 2 < KS) pre = *(const bf16x8*)(aptr + (size_t)(ks + 2) * APL);
        }
        __syncthreads();
    }

#pragma unroll
    for (int rt = 0; rt < 2; rt++) {
#pragma unroll
        for (int ct = 0; ct < 2; ct++) {
            const int col = cpair * 32 + ct * 16 + n16;
            const int rbase = row0 + rpair * 32 + rt * 16 + quad * 4;
#pragma unroll
            for (int r = 0; r < 4; r++) {
                int orow = rbase + r;
                if (orow < N) {
                    Cb[(size_t)orow * M + col] = f2bf(dinv[orow] * acc[rt][ct][r]);
                }
            }
        }
    }
}

// ============ gather2 (XCD channel-half partition) -> fp32 out ============
// grid = 2*GB; h = blockIdx&1 selects channel half [32h,32h+32) of [N][64] rows.
// Round-robin pins half h to XCDs {h,h+2,h+4,h+6}: per-XCD set = 3.2 MB < L2.
__global__ __launch_bounds__(256) void gather_f32_xcd(const unsigned short* __restrict__ hnb,
                                                      const int* __restrict__ rowptr,
                                                      const int* __restrict__ csr_src,
                                                      const float* __restrict__ dinv,
                                                      const float* __restrict__ bias,
                                                      float* __restrict__ outp, int N) {
    const int h = blockIdx.x & 1;
    const int tile = blockIdx.x >> 1;
    const int j = threadIdx.x & 3;    // 8-ch slice within half
    const int r = threadIdx.x >> 2;   // row 0..63
    const int g = tile * 64 + r;
    if (g >= N) return;

    const unsigned short* base = hnb + h * 32 + j * 8;
    float acc[8];
    {
        bf16x8 v = *(const bf16x8*)(base + (size_t)g * 64);  // self-loop
#pragma unroll
        for (int i = 0; i < 8; i++) acc[i] = bf2f((unsigned short)v[i]);
    }
    int e = rowptr[g];
    const int end = rowptr[g + 1];
    for (; e + 3 < end; e += 4) {
        int s0 = csr_src[e];
        int s1 = csr_src[e + 1];
        int s2 = csr_src[e + 2];
        int s3 = csr_src[e + 3];
        bf16x8 v0 = *(const bf16x8*)(base + (size_t)s0 * 64);
        bf16x8 v1 = *(const bf16x8*)(base + (size_t)s1 * 64);
        bf16x8 v2 = *(const bf16x8*)(base + (size_t)s2 * 64);
        bf16x8 v3 = *(const bf16x8*)(base + (size_t)s3 * 64);
#pragma unroll
        for (int i = 0; i < 8; i++) {
            acc[i] += (bf2f((unsigned short)v0[i]) + bf2f((unsigned short)v1[i])) +
                      (bf2f((unsigned short)v2[i]) + bf2f((unsigned short)v3[i]));
        }
    }
    for (; e < end; e++) {
        int s0 = csr_src[e];
        bf16x8 v0 = *(const bf16x8*)(base + (size_t)s0 * 64);
#pragma unroll
        for (int i = 0; i < 8; i++) acc[i] += bf2f((unsigned short)v0[i]);
    }

    const float s = dinv[g];
    float rr[8];
#pragma unroll
    for (int i = 0; i < 8; i++) rr[i] = s * acc[i] + bias[h * 32 + j * 8 + i];
    float* op = outp + (size_t)g * 64 + h * 32 + j * 8;
    *(float4*)(op) = make_float4(rr[0], rr[1], rr[2], rr[3]);
    *(float4*)(op + 4) = make_float4(rr[4], rr[5], rr[6], rr[7]);
}

extern "C" void kernel_launch(void* const* d_in, const int* in_sizes, int n_in,
                              void* d_out, int out_size, void* d_ws, size_t ws_size,
                              hipStream_t stream) {
    const float* x  = (const float*)d_in[0];
    const int*   ei = (const int*)d_in[1];
    const float* W1 = (const float*)d_in[2];
    const float* b1 = (const float*)d_in[3];
    const float* W2 = (const float*)d_in[4];
    const float* b2 = (const float*)d_in[5];

    const int N = N_NODES;
    const int E = in_sizes[1] / 2;
    const int* src = ei;
    const int* dst = ei + E;

    char* ws = (char*)d_ws;
    size_t off = 0;
    auto carve = [&](size_t bytes) {
        char* p = ws + off;
        off += (bytes + 255) & ~(size_t)255;
        return p;
    };
    int*      cnt     = (int*)     carve((size_t)NCH * NBKT * 4);
    int*      offm    = (int*)     carve((size_t)NCH * NBKT * 4);
    int*      total   = (int*)     carve((size_t)NBKT * 4);
    unsigned* pairs   = (unsigned*)carve((size_t)E * 4);
    int*      rowptr  = (int*)     carve((size_t)(N + 1) * 4);
    int*      csr_src = (int*)     carve((size_t)E * 4);
    float*    dinv    = (float*)   carve((size_t)N * 4);
    unsigned short* W1th = (unsigned short*)carve((size_t)256 * 128 * 2);
    unsigned short* W1tl = (unsigned short*)carve((size_t)256 * 128 * 2);
    unsigned short* W2th = (unsigned short*)carve((size_t)128 * 64 * 2);
    unsigned short* W2tl = (unsigned short*)carve((size_t)128 * 64 * 2);
    unsigned short* hn1q = (unsigned short*)carve((size_t)N * 128 * 2);  // bf16, PLANAR 4x[N][32]
    unsigned short* h1q  = (unsigned short*)carve((size_t)N * 128 * 2);  // bf16, PLANAR 4x[N][32]
    unsigned short* hn2b = (unsigned short*)carve((size_t)N * 64 * 2);   // bf16, [N][64]

    const int epc = (E + NCH - 1) / NCH;
    const int nbk = (N + 255) >> 8;  // 196 live buckets
    const int GB = (N + 63) / 64;    // 782 row-tiles

    // ---- CSR build + weight split ----
    prep<<<NCH + 160, 256, 0, stream>>>(dst, cnt, E, epc, W1, W2, W1th, W1tl, W2th, W2tl);
    bkt_scan_chunks<<<NBKT, 256, 0, stream>>>(cnt, offm, total);
    bkt_scatter<<<NCH, 256, 0, stream>>>(src, dst, offm, total, pairs, E, epc);
    bkt_csr<<<nbk, 256, 0, stream>>>(pairs, total, rowptr, csr_src, dinv, N);

    // ---- layer 1 transform (planar out) ----
    gemm_mfma_v4<256, 128><<<GB, 512, 0, stream>>>(x, W1th, W1tl, dinv, hn1q, N);

    // ---- layer 1 aggregate + ReLU (XCD quarter-partitioned) ----
    gather1_xcd<<<4 * GB, 256, 0, stream>>>(hn1q, rowptr, csr_src, dinv, b1, h1q, N);

    // ---- layer 2 transform (planar A in) ----
    gemm_mfma_bfA<128, 64><<<GB, 256, 0, stream>>>(h1q, W2th, W2tl, dinv, hn2b, N);

    // ---- layer 2 aggregate -> fp32 out (XCD half-partitioned) ----
    gather_f32_xcd<<<2 * GB, 256, 0, stream>>>(hn2b, rowptr, csr_src, dinv, b2,
                                               (float*)d_out, N);
}

// Round 8
// 202.050 us; speedup vs baseline: 1.0965x; 1.0264x over previous
//
#include <hip/hip_runtime.h>

#define N_NODES 50000
#define NCH 256          // edge chunks (blocks in count/scatter)
#define NBKT 256         // bucket slots (dst>>8; 196 live for N=50000)

typedef short bf16x8 __attribute__((ext_vector_type(8)));
typedef float f32x4 __attribute__((ext_vector_type(4)));

__device__ inline unsigned short f2bf(float f) {
    union { float f; unsigned u; } v; v.f = f;
    unsigned u = v.u;
    unsigned lsb = (u >> 16) & 1u;
    u += 0x7fffu + lsb;  // round-to-nearest-even
    return (unsigned short)(u >> 16);
}

__device__ inline float bf2f(unsigned short h) {
    union { unsigned u; float f; } v; v.u = ((unsigned)h) << 16;
    return v.f;
}

// ============ prep: bucket histogram (blocks < NCH) + W split (blocks >= NCH) ============
__global__ __launch_bounds__(256) void prep(const int* __restrict__ dst,
                                            int* __restrict__ cnt, int E, int epc,
                                            const float* __restrict__ W1,
                                            const float* __restrict__ W2,
                                            unsigned short* __restrict__ B1h,
                                            unsigned short* __restrict__ B1l,
                                            unsigned short* __restrict__ B2h,
                                            unsigned short* __restrict__ B2l) {
    const int c = blockIdx.x;
    if (c < NCH) {
        __shared__ int h[NBKT];
        h[threadIdx.x] = 0;
        __syncthreads();
        const int e0 = c * epc;
        const int e1 = min(E, e0 + epc);
        for (int e = e0 + threadIdx.x; e < e1; e += 256)
            atomicAdd(&h[dst[e] >> 8], 1);
        __syncthreads();
        cnt[c * NBKT + threadIdx.x] = h[threadIdx.x];
        return;
    }
    // W split into MFMA fragment order:
    // Bf[((g*KS+ks)*64 + quad*16 + n16)*8 + j] = bf16(W^T[g*16+n16][ks*32+quad*8+j])
    int i = (c - NCH) * 256 + threadIdx.x;
    const float* W;
    unsigned short *Th, *Tl;
    int K, logM, idx;
    if (i < 32768) { W = W1; Th = B1h; Tl = B1l; K = 256; logM = 7; idx = i; }
    else if (i < 32768 + 8192) { W = W2; Th = B2h; Tl = B2l; K = 128; logM = 6; idx = i - 32768; }
    else return;
    const int M = 1 << logM;
    const int KS = K / 32;
    int k = idx >> logM;
    int n = idx & (M - 1);
    float v = W[idx];
    unsigned short h = f2bf(v);
    unsigned short l = f2bf(v - bf2f(h));
    int g = n >> 4, n16 = n & 15, ks = k >> 5, quad = (k >> 3) & 3, j = k & 7;
    size_t o = ((size_t)((g * KS + ks) * 64 + quad * 16 + n16)) * 8 + j;
    Th[o] = h;
    Tl[o] = l;
}

// S1: per-bucket exclusive scan over chunks; off[c][b], total[b]
__global__ __launch_bounds__(256) void bkt_scan_chunks(const int* __restrict__ cnt,
                                                       int* __restrict__ off,
                                                       int* __restrict__ total) {
    __shared__ int sh[256];
    const int b = blockIdx.x;
    const int t = threadIdx.x;
    int v = cnt[t * NBKT + b];
    sh[t] = v;
    __syncthreads();
    for (int o = 1; o < 256; o <<= 1) {
        int u = (t >= o) ? sh[t - o] : 0;
        __syncthreads();
        sh[t] += u;
        __syncthreads();
    }
    off[t * NBKT + b] = sh[t] - v;
    if (t == 255) total[b] = sh[255];
}

// S2: scan totals -> bbase[0..256]; rowptr[N]=E
__global__ __launch_bounds__(256) void bkt_scan_base(const int* __restrict__ total,
                                                     int* __restrict__ bbase,
                                                     int* __restrict__ rowptr,
                                                     int N, int E) {
    __shared__ int sh[256];
    const int t = threadIdx.x;
    int v = total[t];
    sh[t] = v;
    __syncthreads();
    for (int o = 1; o < 256; o <<= 1) {
        int u = (t >= o) ? sh[t - o] : 0;
        __syncthreads();
        sh[t] += u;
        __syncthreads();
    }
    bbase[t] = sh[t] - v;
    if (t == 255) bbase[256] = sh[255];
    if (t == 0) rowptr[N] = E;
}

// B2: scatter packed (src<<8 | dst&255) into bucket-sorted order; LDS cursors
__global__ __launch_bounds__(256) void bkt_scatter(const int* __restrict__ src,
                                                   const int* __restrict__ dst,
                                                   const int* __restrict__ off,
                                                   const int* __restrict__ bbase,
                                                   unsigned* __restrict__ pairs,
                                                   int E, int epc) {
    __shared__ int cur[NBKT];
    const int c = blockIdx.x;
    cur[threadIdx.x] = bbase[threadIdx.x] + off[c * NBKT + threadIdx.x];
    __syncthreads();
    const int e0 = c * epc;
    const int e1 = min(E, e0 + epc);
    for (int e = e0 + threadIdx.x; e < e1; e += 256) {
        int s = src[e];
        int d = dst[e];
        int pos = atomicAdd(&cur[d >> 8], 1);
        pairs[pos] = ((unsigned)s << 8) | (unsigned)(d & 255);
    }
}

// B3: per-bucket local CSR: rowptr, dinv, csr_src (dense regional writes)
__global__ __launch_bounds__(256) void bkt_csr(const unsigned* __restrict__ pairs,
                                               const int* __restrict__ bbase,
                                               int* __restrict__ rowptr,
                                               int* __restrict__ csr_src,
                                               float* __restrict__ dinv, int N) {
    __shared__ int lh[256];
    __shared__ int sc[256];
    __shared__ int lcur[256];
    const int b = blockIdx.x;
    const int t = threadIdx.x;
    const int ebase = bbase[b];
    const int eend = bbase[b + 1];
    const int node0 = b << 8;

    lh[t] = 0;
    __syncthreads();
    for (int e = ebase + t; e < eend; e += 256)
        atomicAdd(&lh[pairs[e] & 255u], 1);
    __syncthreads();
    int v = lh[t];
    sc[t] = v;
    __syncthreads();
    for (int o = 1; o < 256; o <<= 1) {
        int u = (t >= o) ? sc[t - o] : 0;
        __syncthreads();
        sc[t] += u;
        __syncthreads();
    }
    const int excl = sc[t] - v;
    lcur[t] = ebase + excl;
    const int node = node0 + t;
    if (node < N) {
        rowptr[node] = ebase + excl;
        dinv[node] = rsqrtf((float)(v + 1));  // +1 self-loop
    }
    __syncthreads();
    for (int e = ebase + t; e < eend; e += 256) {
        unsigned p = pairs[e];
        int pos = atomicAdd(&lcur[p & 255u], 1);
        csr_src[pos] = (int)(p >> 8);
    }
}

// ============ MFMA GEMM (layer1): fp32 A -> 3-term split, 32x32/wave,
//              rolling B, dbuf LDS, bf16 monolithic out ============
template <int K, int M>
__global__ __launch_bounds__(M * 4) void gemm_mfma_v4(const float* __restrict__ A,
                                                      const unsigned short* __restrict__ Bfh,
                                                      const unsigned short* __restrict__ Bfl,
                                                      const float* __restrict__ dinv,
                                                      unsigned short* __restrict__ Cb, int N) {
    const int KS = K / 32;
    const int THREADS = M * 4;
    const int CPT = 512 / THREADS;
    const int PL = 64 * 40;
    const int CPAIRS = M / 32;

    __shared__ __align__(16) unsigned short Ah[2 * PL];
    __shared__ __align__(16) unsigned short Al[2 * PL];

    const int tid = threadIdx.x;
    const int wave = tid >> 6;
    const int lane = tid & 63;
    const int n16 = lane & 15;
    const int quad = lane >> 4;
    const int cpair = wave & (CPAIRS - 1);
    const int rpair = wave / CPAIRS;
    const int row0 = blockIdx.x * 64;

    bf16x8 bh[2][2], bl[2][2];
    auto loadB = [&](int ks, int par) {
#pragma unroll
        for (int ct = 0; ct < 2; ct++) {
            const int g = cpair * 2 + ct;
            const size_t o = ((size_t)(g * KS + ks) * 64 + lane) * 8;
            bh[par][ct] = *(const bf16x8*)(Bfh + o);
            bl[par][ct] = *(const bf16x8*)(Bfl + o);
        }
    };
    loadB(0, 0);

    int srow[CPT], sc4[CPT];
    const float* aptr[CPT];
#pragma unroll
    for (int p = 0; p < CPT; p++) {
        int q = p * THREADS + tid;
        srow[p] = q >> 3;
        sc4[p] = q & 7;
        int grow = row0 + srow[p];
        if (grow >= N) grow = N - 1;
        aptr[p] = A + (size_t)grow * K + sc4[p] * 4;
    }

    float4 pre[CPT];
#pragma unroll
    for (int p = 0; p < CPT; p++) pre[p] = *(const float4*)(aptr[p]);

#pragma unroll
    for (int p = 0; p < CPT; p++) {
        ushort4 h4, l4;
        unsigned short* hp = (unsigned short*)&h4;
        unsigned short* lp = (unsigned short*)&l4;
        float av[4] = {pre[p].x, pre[p].y, pre[p].z, pre[p].w};
#pragma unroll
        for (int j = 0; j < 4; j++) {
            unsigned short h = f2bf(av[j]);
            hp[j] = h;
            lp[j] = f2bf(av[j] - bf2f(h));
        }
        *(ushort4*)(Ah + srow[p] * 40 + sc4[p] * 4) = h4;
        *(ushort4*)(Al + srow[p] * 40 + sc4[p] * 4) = l4;
    }
    if (KS > 1) {
#pragma unroll
        for (int p = 0; p < CPT; p++) pre[p] = *(const float4*)(aptr[p] + 32);
    }
    __syncthreads();

    f32x4 acc[2][2] = {};

#pragma unroll
    for (int ks = 0; ks < KS; ks++) {
        const int cur = ks & 1;
        if (ks + 1 < KS) loadB(ks + 1, cur ^ 1);
#pragma unroll
        for (int rt = 0; rt < 2; rt++) {
            const int ro = cur * PL + (rpair * 32 + rt * 16 + n16) * 40 + quad * 8;
            bf16x8 ah = *(const bf16x8*)(Ah + ro);
            bf16x8 al = *(const bf16x8*)(Al + ro);
#pragma unroll
            for (int ct = 0; ct < 2; ct++) {
                acc[rt][ct] = __builtin_amdgcn_mfma_f32_16x16x32_bf16(ah, bh[cur][ct], acc[rt][ct], 0, 0, 0);
                acc[rt][ct] = __builtin_amdgcn_mfma_f32_16x16x32_bf16(ah, bl[cur][ct], acc[rt][ct], 0, 0, 0);
                acc[rt][ct] = __builtin_amdgcn_mfma_f32_16x16x32_bf16(al, bh[cur][ct], acc[rt][ct], 0, 0, 0);
            }
        }
        if (ks + 1 < KS) {
            const int nxt = (cur ^ 1) * PL;
#pragma unroll
            for (int p = 0; p < CPT; p++) {
                ushort4 h4, l4;
                unsigned short* hp = (unsigned short*)&h4;
                unsigned short* lp = (unsigned short*)&l4;
                float av[4] = {pre[p].x, pre[p].y, pre[p].z, pre[p].w};
#pragma unroll
                for (int j = 0; j < 4; j++) {
                    unsigned short h = f2bf(av[j]);
                    hp[j] = h;
                    lp[j] = f2bf(av[j] - bf2f(h));
                }
                *(ushort4*)(Ah + nxt + srow[p] * 40 + sc4[p] * 4) = h4;
                *(ushort4*)(Al + nxt + srow[p] * 40 + sc4[p] * 4) = l4;
            }
            if (ks + 2 < KS) {
#pragma unroll
                for (int p = 0; p < CPT; p++)
                    pre[p] = *(const float4*)(aptr[p] + (ks + 2) * 32);
            }
        }
        __syncthreads();
    }

#pragma unroll
    for (int rt = 0; rt < 2; rt++) {
#pragma unroll
        for (int ct = 0; ct < 2; ct++) {
            const int col = cpair * 32 + ct * 16 + n16;
            const int rbase = row0 + rpair * 32 + rt * 16 + quad * 4;
#pragma unroll
            for (int r = 0; r < 4; r++) {
                int orow = rbase + r;
                if (orow < N) {
                    Cb[(size_t)orow * M + col] = f2bf(dinv[orow] * acc[rt][ct][r]);
                }
            }
        }
    }
}

// ============ MFMA GEMM (layer2): bf16 A direct-stage (no split), 2 MFMA/step ============
template <int K, int M>
__global__ __launch_bounds__(M * 4) void gemm_mfma_bfA(const unsigned short* __restrict__ A,
                                                       const unsigned short* __restrict__ Bfh,
                                                       const unsigned short* __restrict__ Bfl,
                                                       const float* __restrict__ dinv,
                                                       unsigned short* __restrict__ Cb, int N) {
    const int KS = K / 32;
    const int PL = 64 * 40;
    const int CPAIRS = M / 32;

    __shared__ __align__(16) unsigned short Ah[2 * PL];

    const int tid = threadIdx.x;
    const int wave = tid >> 6;
    const int lane = tid & 63;
    const int n16 = lane & 15;
    const int quad = lane >> 4;
    const int cpair = wave & (CPAIRS - 1);
    const int rpair = wave / CPAIRS;
    const int row0 = blockIdx.x * 64;

    bf16x8 bh[2][2], bl[2][2];
    auto loadB = [&](int ks, int par) {
#pragma unroll
        for (int ct = 0; ct < 2; ct++) {
            const int g = cpair * 2 + ct;
            const size_t o = ((size_t)(g * KS + ks) * 64 + lane) * 8;
            bh[par][ct] = *(const bf16x8*)(Bfh + o);
            bl[par][ct] = *(const bf16x8*)(Bfl + o);
        }
    };
    loadB(0, 0);

    // A staging: 64 rows x 32 cols bf16 = 256 chunks of 8 ushorts
    const int srow = tid >> 2;
    const int sc8 = tid & 3;
    const unsigned short* aptr;
    {
        int grow = row0 + srow;
        if (grow >= N) grow = N - 1;
        aptr = A + (size_t)grow * K + sc8 * 8;
    }

    bf16x8 pre = *(const bf16x8*)(aptr);

    {
        ushort4* d0 = (ushort4*)(Ah + srow * 40 + sc8 * 8);
        ushort4 lo, hi;
        unsigned short* lp = (unsigned short*)&lo;
        unsigned short* hp = (unsigned short*)&hi;
#pragma unroll
        for (int j = 0; j < 4; j++) { lp[j] = (unsigned short)pre[j]; hp[j] = (unsigned short)pre[j + 4]; }
        d0[0] = lo;
        d0[1] = hi;
    }
    if (KS > 1) pre = *(const bf16x8*)(aptr + 32);
    __syncthreads();

    f32x4 acc[2][2] = {};

#pragma unroll
    for (int ks = 0; ks < KS; ks++) {
        const int cur = ks & 1;
        if (ks + 1 < KS) loadB(ks + 1, cur ^ 1);
#pragma unroll
        for (int rt = 0; rt < 2; rt++) {
            const int ro = cur * PL + (rpair * 32 + rt * 16 + n16) * 40 + quad * 8;
            bf16x8 ah = *(const bf16x8*)(Ah + ro);
#pragma unroll
            for (int ct = 0; ct < 2; ct++) {
                acc[rt][ct] = __builtin_amdgcn_mfma_f32_16x16x32_bf16(ah, bh[cur][ct], acc[rt][ct], 0, 0, 0);
                acc[rt][ct] = __builtin_amdgcn_mfma_f32_16x16x32_bf16(ah, bl[cur][ct], acc[rt][ct], 0, 0, 0);
            }
        }
        if (ks + 1 < KS) {
            const int nxt = (cur ^ 1) * PL;
            ushort4* d0 = (ushort4*)(Ah + nxt + srow * 40 + sc8 * 8);
            ushort4 lo, hi;
            unsigned short* lp = (unsigned short*)&lo;
            unsigned short* hp = (unsigned short*)&hi;
#pragma unroll
            for (int j = 0; j < 4; j++) { lp[j] = (unsigned short)pre[j]; hp[j] = (unsigned short)pre[j + 4]; }
            d0[0] = lo;
            d0[1] = hi;
            if (ks + 2 < KS) pre = *(const bf16x8*)(aptr + (ks + 2) * 32);
        }
        __syncthreads();
    }

#pragma unroll
    for (int rt = 0; rt < 2; rt++) {
#pragma unroll
        for (int ct = 0; ct < 2; ct++) {
            const int col = cpair * 32 + ct * 16 + n16;
            const int rbase = row0 + rpair * 32 + rt * 16 + quad * 4;
#pragma unroll
            for (int r = 0; r < 4; r++) {
                int orow = rbase + r;
                if (orow < N) {
                    Cb[(size_t)orow * M + col] = f2bf(dinv[orow] * acc[rt][ct][r]);
                }
            }
        }
    }
}

// ============ gather-aggregate (bf16 rows in) -> bf16 out (+ReLU) ============
template <int M>
__global__ __launch_bounds__(256) void gather_to_bf16(const unsigned short* __restrict__ hnb,
                                                      const int* __restrict__ rowptr,
                                                      const int* __restrict__ csr_src,
                                                      const float* __restrict__ dinv,
                                                      const float* __restrict__ bias,
                                                      unsigned short* __restrict__ outp, int n) {
    const int MQ = M / 8;
    const int GPB = 256 / MQ;
    int g = blockIdx.x * GPB + threadIdx.x / MQ;
    int j = threadIdx.x % MQ;
    if (g >= n) return;

    float acc[8];
    {
        bf16x8 v = *(const bf16x8*)(hnb + (size_t)g * M + j * 8);  // self-loop
#pragma unroll
        for (int i = 0; i < 8; i++) acc[i] = bf2f((unsigned short)v[i]);
    }

    int e = rowptr[g];
    const int end = rowptr[g + 1];
    for (; e + 3 < end; e += 4) {
        int s0 = csr_src[e];
        int s1 = csr_src[e + 1];
        int s2 = csr_src[e + 2];
        int s3 = csr_src[e + 3];
        bf16x8 v0 = *(const bf16x8*)(hnb + (size_t)s0 * M + j * 8);
        bf16x8 v1 = *(const bf16x8*)(hnb + (size_t)s1 * M + j * 8);
        bf16x8 v2 = *(const bf16x8*)(hnb + (size_t)s2 * M + j * 8);
        bf16x8 v3 = *(const bf16x8*)(hnb + (size_t)s3 * M + j * 8);
#pragma unroll
        for (int i = 0; i < 8; i++) {
            acc[i] += (bf2f((unsigned short)v0[i]) + bf2f((unsigned short)v1[i])) +
                      (bf2f((unsigned short)v2[i]) + bf2f((unsigned short)v3[i]));
        }
    }
    for (; e < end; e++) {
        int s0 = csr_src[e];
        bf16x8 v0 = *(const bf16x8*)(hnb + (size_t)s0 * M + j * 8);
#pragma unroll
        for (int i = 0; i < 8; i++) acc[i] += bf2f((unsigned short)v0[i]);
    }

    const float s = dinv[g];
    bf16x8 r;
#pragma unroll
    for (int i = 0; i < 8; i++) {
        float t = fmaxf(s * acc[i] + bias[j * 8 + i], 0.0f);  // ReLU
        r[i] = (short)f2bf(t);
    }
    *(bf16x8*)(outp + (size_t)g * M + j * 8) = r;
}

// ============ gather-aggregate (bf16 rows in) -> fp32 out (no ReLU) ============
template <int M>
__global__ __launch_bounds__(256) void gather_to_f32(const unsigned short* __restrict__ hnb,
                                                     const int* __restrict__ rowptr,
                                                     const int* __restrict__ csr_src,
                                                     const float* __restrict__ dinv,
                                                     const float* __restrict__ bias,
                                                     float* __restrict__ outp, int n) {
    const int MQ = M / 8;
    const int GPB = 256 / MQ;
    int g = blockIdx.x * GPB + threadIdx.x / MQ;
    int j = threadIdx.x % MQ;
    if (g >= n) return;

    float acc[8];
    {
        bf16x8 v = *(const bf16x8*)(hnb + (size_t)g * M + j * 8);  // self-loop
#pragma unroll
        for (int i = 0; i < 8; i++) acc[i] = bf2f((unsigned short)v[i]);
    }

    int e = rowptr[g];
    const int end = rowptr[g + 1];
    for (; e + 3 < end; e += 4) {
        int s0 = csr_src[e];
        int s1 = csr_src[e + 1];
        int s2 = csr_src[e + 2];
        int s3 = csr_src[e + 3];
        bf16x8 v0 = *(const bf16x8*)(hnb + (size_t)s0 * M + j * 8);
        bf16x8 v1 = *(const bf16x8*)(hnb + (size_t)s1 * M + j * 8);
        bf16x8 v2 = *(const bf16x8*)(hnb + (size_t)s2 * M + j * 8);
        bf16x8 v3 = *(const bf16x8*)(hnb + (size_t)s3 * M + j * 8);
#pragma unroll
        for (int i = 0; i < 8; i++) {
            acc[i] += (bf2f((unsigned short)v0[i]) + bf2f((unsigned short)v1[i])) +
                      (bf2f((unsigned short)v2[i]) + bf2f((unsigned short)v3[i]));
        }
    }
    for (; e < end; e++) {
        int s0 = csr_src[e];
        bf16x8 v0 = *(const bf16x8*)(hnb + (size_t)s0 * M + j * 8);
#pragma unroll
        for (int i = 0; i < 8; i++) acc[i] += bf2f((unsigned short)v0[i]);
    }

    const float s = dinv[g];
    float r[8];
#pragma unroll
    for (int i = 0; i < 8; i++) r[i] = s * acc[i] + bias[j * 8 + i];
    float* op = outp + (size_t)g * M + j * 8;
    *(float4*)(op) = make_float4(r[0], r[1], r[2], r[3]);
    *(float4*)(op + 4) = make_float4(r[4], r[5], r[6], r[7]);
}

extern "C" void kernel_launch(void* const* d_in, const int* in_sizes, int n_in,
                              void* d_out, int out_size, void* d_ws, size_t ws_size,
                              hipStream_t stream) {
    const float* x  = (const float*)d_in[0];
    const int*   ei = (const int*)d_in[1];
    const float* W1 = (const float*)d_in[2];
    const float* b1 = (const float*)d_in[3];
    const float* W2 = (const float*)d_in[4];
    const float* b2 = (const float*)d_in[5];

    const int N = N_NODES;
    const int E = in_sizes[1] / 2;
    const int* src = ei;
    const int* dst = ei + E;

    char* ws = (char*)d_ws;
    size_t off = 0;
    auto carve = [&](size_t bytes) {
        char* p = ws + off;
        off += (bytes + 255) & ~(size_t)255;
        return p;
    };
    int*      cnt     = (int*)     carve((size_t)NCH * NBKT * 4);
    int*      offm    = (int*)     carve((size_t)NCH * NBKT * 4);
    int*      total   = (int*)     carve((size_t)NBKT * 4);
    int*      bbase   = (int*)     carve((size_t)(NBKT + 1) * 4);
    unsigned* pairs   = (unsigned*)carve((size_t)E * 4);
    int*      rowptr  = (int*)     carve((size_t)(N + 1) * 4);
    int*      csr_src = (int*)     carve((size_t)E * 4);
    float*    dinv    = (float*)   carve((size_t)N * 4);
    unsigned short* W1th = (unsigned short*)carve((size_t)256 * 128 * 2);
    unsigned short* W1tl = (unsigned short*)carve((size_t)256 * 128 * 2);
    unsigned short* W2th = (unsigned short*)carve((size_t)128 * 64 * 2);
    unsigned short* W2tl = (unsigned short*)carve((size_t)128 * 64 * 2);
    unsigned short* hn1b = (unsigned short*)carve((size_t)N * 128 * 2);  // bf16
    unsigned short* h1b  = (unsigned short*)carve((size_t)N * 128 * 2);  // bf16
    unsigned short* hn2b = hn1b;  // hn1b dead after gather1

    const int epc = (E + NCH - 1) / NCH;
    const int nbk = (N + 255) >> 8;  // 196 live buckets

    // ---- CSR build + weight split ----
    prep<<<NCH + 160, 256, 0, stream>>>(dst, cnt, E, epc, W1, W2, W1th, W1tl, W2th, W2tl);
    bkt_scan_chunks<<<NBKT, 256, 0, stream>>>(cnt, offm, total);
    bkt_scan_base<<<1, 256, 0, stream>>>(total, bbase, rowptr, N, E);
    bkt_scatter<<<NCH, 256, 0, stream>>>(src, dst, offm, bbase, pairs, E, epc);
    bkt_csr<<<nbk, 256, 0, stream>>>(pairs, bbase, rowptr, csr_src, dinv, N);

    const int GB = (N + 63) / 64;  // 782 blocks

    // ---- layer 1 ----
    gemm_mfma_v4<256, 128><<<GB, 512, 0, stream>>>(x, W1th, W1tl, dinv, hn1b, N);
    {
        const int GPB = 256 / (128 / 8);  // 16 nodes/block
        gather_to_bf16<128><<<(N + GPB - 1) / GPB, 256, 0, stream>>>(
            hn1b, rowptr, csr_src, dinv, b1, h1b, N);
    }

    // ---- layer 2 ----
    gemm_mfma_bfA<128, 64><<<GB, 256, 0, stream>>>(h1b, W2th, W2tl, dinv, hn2b, N);
    {
        const int GPB = 256 / (64 / 8);  // 32 nodes/block
        gather_to_f32<64><<<(N + GPB - 1) / GPB, 256, 0, stream>>>(
            hn2b, rowptr, csr_src, dinv, b2, (float*)d_out, N);
    }
}